// Round 6
// baseline (262.826 us; speedup 1.0000x reference)
//
#include <hip/hip_runtime.h>
#include <stdint.h>

#define HID 1024
#define NEXP 8
#define NTOK 16384
#define CAP 8192

typedef __attribute__((ext_vector_type(8))) __bf16 bf16x8;
typedef __attribute__((ext_vector_type(8))) short short8;
typedef __attribute__((ext_vector_type(4))) float f32x4;

__device__ __forceinline__ ushort f2bf(float f) {
  uint32_t u = __builtin_bit_cast(uint32_t, f);
  u += 0x7FFF + ((u >> 16) & 1);          // round-to-nearest-even
  return (ushort)(u >> 16);
}
__device__ __forceinline__ float bf2f(ushort u) {
  return __builtin_bit_cast(float, (uint32_t)u << 16);
}

__device__ __forceinline__ void gl16(const void* g, void* l) {
  __builtin_amdgcn_global_load_lds((__attribute__((address_space(1))) void*)(g),
                                   (__attribute__((address_space(3))) void*)(l),
                                   16, 0, 0);
}

// ---------------- fp32 -> bf16 conversion (weights only) ----------------
__global__ void cvt_kernel(const float* __restrict__ src, ushort* __restrict__ dst, int n4) {
  int i = blockIdx.x * blockDim.x + threadIdx.x;
  int stride = gridDim.x * blockDim.x;
  for (; i < n4; i += stride) {
    float4 v = reinterpret_cast<const float4*>(src)[i];
    ushort4 o = make_ushort4(f2bf(v.x), f2bf(v.y), f2bf(v.z), f2bf(v.w));
    reinterpret_cast<ushort4*>(dst)[i] = o;
  }
}

__global__ void zero_kernel(int* counts) {
  if (threadIdx.x < 16) counts[threadIdx.x] = 0;   // counts[0..7] + ticket at [8]
}

// ---------------- gate: fp32 logits + fused tokens->bf16 cvt; NO atomics ----------------
__global__ __launch_bounds__(256) void gate_kernel(
    const float* __restrict__ tokens, const float* __restrict__ gate_w,
    ushort* __restrict__ Xb,
    uint32_t* __restrict__ tinfo, float2* __restrict__ tw) {
  const int lane = threadIdx.x & 63;
  const int wave = threadIdx.x >> 6;
  float4 rg[NEXP][4];
#pragma unroll
  for (int e = 0; e < NEXP; e++)
#pragma unroll
    for (int j = 0; j < 4; j++)
      rg[e][j] = reinterpret_cast<const float4*>(gate_w)[e * 256 + j * 64 + lane];

  const int gwid = blockIdx.x * 4 + wave;
  const int nw = gridDim.x * 4;
  for (int t = gwid; t < NTOK; t += nw) {
    const float4* xr = reinterpret_cast<const float4*>(tokens + (size_t)t * HID);
    float acc[NEXP];
#pragma unroll
    for (int e = 0; e < NEXP; e++) acc[e] = 0.f;
    ushort4 xs[4];
#pragma unroll
    for (int j = 0; j < 4; j++) {
      float4 x = xr[j * 64 + lane];
      xs[j] = make_ushort4(f2bf(x.x), f2bf(x.y), f2bf(x.z), f2bf(x.w));
#pragma unroll
      for (int e = 0; e < NEXP; e++) {
        acc[e] = fmaf(x.x, rg[e][j].x,
                 fmaf(x.y, rg[e][j].y,
                 fmaf(x.z, rg[e][j].z,
                 fmaf(x.w, rg[e][j].w, acc[e]))));
      }
    }
    ushort4* xo = reinterpret_cast<ushort4*>(Xb + (size_t)t * HID);
#pragma unroll
    for (int j = 0; j < 4; j++) xo[j * 64 + lane] = xs[j];
#pragma unroll
    for (int e = 0; e < NEXP; e++) {
#pragma unroll
      for (int s = 32; s > 0; s >>= 1) acc[e] += __shfl_xor(acc[e], s);
    }
    int i1 = 0;
#pragma unroll
    for (int e = 1; e < NEXP; e++) if (acc[e] > acc[i1]) i1 = e;
    int i2 = (i1 == 0) ? 1 : 0;
#pragma unroll
    for (int e = 0; e < NEXP; e++) if (e != i1 && acc[e] > acc[i2]) i2 = e;
    float m = acc[i1];
    float s = 0.f;
#pragma unroll
    for (int e = 0; e < NEXP; e++) s += __expf(acc[e] - m);
    float w1 = 1.f / s;
    float w2 = __expf(acc[i2] - m) / s;
    if (lane == 0) {
      tinfo[t] = (uint32_t)i1 | ((uint32_t)i2 << 8);
      tw[t] = make_float2(w1, w2);
    }
  }
}

// ---------------- scatter: block-aggregated list build ----------------
__global__ __launch_bounds__(256) void scatter_kernel(
    const uint32_t* __restrict__ tinfo, const float2* __restrict__ tw,
    int* __restrict__ list, float* __restrict__ listw, int* __restrict__ counts) {
  __shared__ int lhist[NEXP];
  __shared__ int gbase[NEXP];
  const int tid = threadIdx.x;
  if (tid < NEXP) lhist[tid] = 0;
  __syncthreads();
  const int t = blockIdx.x * 256 + tid;
  uint32_t info = tinfo[t];
  int i1 = info & 0xFF, i2 = (info >> 8) & 0xFF;
  float2 w = tw[t];
  int lr1 = atomicAdd(&lhist[i1], 1);
  int lr2 = atomicAdd(&lhist[i2], 1);
  __syncthreads();
  if (tid < NEXP) gbase[tid] = atomicAdd(&counts[tid], lhist[tid]);
  __syncthreads();
  int p1 = gbase[i1] + lr1;
  if (p1 < CAP) { list[i1 * CAP + p1] = t;           listw[i1 * CAP + p1] = w.x; }
  int p2 = gbase[i2] + lr2;
  if (p2 < CAP) { list[i2 * CAP + p2] = t | 0x10000; listw[i2 * CAP + p2] = w.y; }
}

// ---------------- expert GEMM: persistent blocks + 256x256x64 8-phase schedule ----------------
// Grid = 256 (1 block/CU, 128 KiB LDS). Blocks pull (e,rt,ct) tiles from a global
// ticket counter (counts[8] slot). Tile body = verified 8-phase m201-style loop.
__global__ __launch_bounds__(512, 2) void egemm_kernel(
    const ushort* __restrict__ Ab, const ushort* __restrict__ Bb,
    const float* __restrict__ bias,
    const int* __restrict__ list, const float* __restrict__ listw,
    int* __restrict__ counts, ushort* __restrict__ contrib) {
  __shared__ __align__(16) ushort As2[2 * 16384];
  __shared__ __align__(16) ushort Bs2[2 * 16384];
  __shared__ int sh_tkt;
  const int tid = threadIdx.x, lane = tid & 63, wid = tid >> 6;

  // total active tiles (uniform across all threads/blocks)
  int tot = 0;
#pragma unroll
  for (int e = 0; e < NEXP; e++) {
    int c = counts[e]; if (c > CAP) c = CAP;
    tot += ((c + 255) >> 8) * 4;
  }

  // ---- ticket-independent geometry ----
  const int srow = wid * 8 + (lane >> 3);            // row within 64-row sweep
  const int sgr  = (lane & 7) ^ ((lane >> 3) & 7);   // pre-swizzled source granule
  const int fr = lane & 15, fq = lane >> 4;
  const int wm = wid >> 2, wn = wid & 3;
  const int c0 = (fq ^ (fr & 7)) * 8;
  const int c1 = ((4 + fq) ^ (fr & 7)) * 8;
  const ushort* pa0 = As2 + wm * 8192 + fr * 64 + c0;
  const ushort* pa1 = As2 + wm * 8192 + fr * 64 + c1;
  const ushort* pb0 = Bs2 + wn * 4096 + fr * 64 + c0;
  const ushort* pb1 = Bs2 + wn * 4096 + fr * 64 + c1;
  ushort* AsP = As2;
  ushort* BsP = Bs2;

  for (;;) {
    __syncthreads();   // drains vmcnt/lgkmcnt (stray stages + epilogue) & protects sh_tkt
    if (tid == 0) sh_tkt = atomicAdd(&counts[8], 1);
    __syncthreads();
    const int tk = sh_tkt;
    if (tk >= tot) break;

    // map ticket -> (e, rt, ct), ct-innermost
    int e = 0, le = tk;
    for (;;) {
      int c = counts[e]; if (c > CAP) c = CAP;
      int te = ((c + 255) >> 8) * 4;
      if (le < te) break;
      le -= te; e++;
    }
    int count = counts[e]; if (count > CAP) count = CAP;
    const int rt = le >> 2, ct = le & 3;

    // ---- per-tile staging pointers (gathered A rows) ----
    int tok[2][2];
#pragma unroll
    for (int h = 0; h < 2; h++)
#pragma unroll
      for (int s = 0; s < 2; s++) {
        int r = rt * 256 + h * 128 + s * 64 + srow;
        tok[h][s] = (r < count) ? (list[e * CAP + r] & 0xFFFF) : 0;
      }
    const ushort* pA[2][2];
    const ushort* pB[2][2];
#pragma unroll
    for (int h = 0; h < 2; h++)
#pragma unroll
      for (int s = 0; s < 2; s++) {
        pA[h][s] = Ab + (size_t)tok[h][s] * HID + sgr * 8;
        pB[h][s] = Bb + (size_t)e * HID * HID +
                   (size_t)(ct * 256 + h * 128 + s * 64 + srow) * HID + sgr * 8;
      }

    f32x4 acc[8][4];
#pragma unroll
    for (int m = 0; m < 8; m++)
#pragma unroll
      for (int n = 0; n < 4; n++) acc[m][n] = (f32x4){0.f, 0.f, 0.f, 0.f};
    bf16x8 bfr[4][2];
    bf16x8 a00, a01, a10, a11;

#define STA(BUF, H, T) do { \
    gl16(pA[H][0] + (T) * 64, AsP + (BUF) * 16384 + (H) * 8192 + wid * 512); \
    gl16(pA[H][1] + (T) * 64, AsP + (BUF) * 16384 + (H) * 8192 + 4096 + wid * 512); } while (0)
#define STB(BUF, H, T) do { \
    gl16(pB[H][0] + (T) * 64, BsP + (BUF) * 16384 + (H) * 8192 + wid * 512); \
    gl16(pB[H][1] + (T) * 64, BsP + (BUF) * 16384 + (H) * 8192 + 4096 + wid * 512); } while (0)
#define BLD(B16K) do { \
    bfr[0][0] = *(const bf16x8*)(pb0 + (B16K));        bfr[0][1] = *(const bf16x8*)(pb1 + (B16K)); \
    bfr[1][0] = *(const bf16x8*)(pb0 + (B16K) + 1024); bfr[1][1] = *(const bf16x8*)(pb1 + (B16K) + 1024); \
    bfr[2][0] = *(const bf16x8*)(pb0 + (B16K) + 2048); bfr[2][1] = *(const bf16x8*)(pb1 + (B16K) + 2048); \
    bfr[3][0] = *(const bf16x8*)(pb0 + (B16K) + 3072); bfr[3][1] = *(const bf16x8*)(pb1 + (B16K) + 3072); } while (0)
#define ALD(B16K, M0) do { \
    a00 = *(const bf16x8*)(pa0 + (B16K) + (M0) * 1024); \
    a01 = *(const bf16x8*)(pa1 + (B16K) + (M0) * 1024); \
    a10 = *(const bf16x8*)(pa0 + (B16K) + ((M0) + 1) * 1024); \
    a11 = *(const bf16x8*)(pa1 + (B16K) + ((M0) + 1) * 1024); } while (0)
#define FMQ(M0) do { \
    acc[M0][0]   = __builtin_amdgcn_mfma_f32_16x16x32_bf16(a00, bfr[0][0], acc[M0][0], 0, 0, 0); \
    acc[M0][0]   = __builtin_amdgcn_mfma_f32_16x16x32_bf16(a01, bfr[0][1], acc[M0][0], 0, 0, 0); \
    acc[M0][1]   = __builtin_amdgcn_mfma_f32_16x16x32_bf16(a00, bfr[1][0], acc[M0][1], 0, 0, 0); \
    acc[M0][1]   = __builtin_amdgcn_mfma_f32_16x16x32_bf16(a01, bfr[1][1], acc[M0][1], 0, 0, 0); \
    acc[M0][2]   = __builtin_amdgcn_mfma_f32_16x16x32_bf16(a00, bfr[2][0], acc[M0][2], 0, 0, 0); \
    acc[M0][2]   = __builtin_amdgcn_mfma_f32_16x16x32_bf16(a01, bfr[2][1], acc[M0][2], 0, 0, 0); \
    acc[M0][3]   = __builtin_amdgcn_mfma_f32_16x16x32_bf16(a00, bfr[3][0], acc[M0][3], 0, 0, 0); \
    acc[M0][3]   = __builtin_amdgcn_mfma_f32_16x16x32_bf16(a01, bfr[3][1], acc[M0][3], 0, 0, 0); \
    acc[M0+1][0] = __builtin_amdgcn_mfma_f32_16x16x32_bf16(a10, bfr[0][0], acc[M0+1][0], 0, 0, 0); \
    acc[M0+1][0] = __builtin_amdgcn_mfma_f32_16x16x32_bf16(a11, bfr[0][1], acc[M0+1][0], 0, 0, 0); \
    acc[M0+1][1] = __builtin_amdgcn_mfma_f32_16x16x32_bf16(a10, bfr[1][0], acc[M0+1][1], 0, 0, 0); \
    acc[M0+1][1] = __builtin_amdgcn_mfma_f32_16x16x32_bf16(a11, bfr[1][1], acc[M0+1][1], 0, 0, 0); \
    acc[M0+1][2] = __builtin_amdgcn_mfma_f32_16x16x32_bf16(a10, bfr[2][0], acc[M0+1][2], 0, 0, 0); \
    acc[M0+1][2] = __builtin_amdgcn_mfma_f32_16x16x32_bf16(a11, bfr[2][1], acc[M0+1][2], 0, 0, 0); \
    acc[M0+1][3] = __builtin_amdgcn_mfma_f32_16x16x32_bf16(a10, bfr[3][0], acc[M0+1][3], 0, 0, 0); \
    acc[M0+1][3] = __builtin_amdgcn_mfma_f32_16x16x32_bf16(a11, bfr[3][1], acc[M0+1][3], 0, 0, 0); } while (0)
#define BAR __builtin_amdgcn_s_barrier()
#define LGKM0 do { asm volatile("s_waitcnt lgkmcnt(0)" ::: "memory"); __builtin_amdgcn_sched_barrier(0); } while (0)
#define VM4 asm volatile("s_waitcnt vmcnt(4)" ::: "memory")
#define SP1 __builtin_amdgcn_s_setprio(1)
#define SP0 __builtin_amdgcn_s_setprio(0)

    // prologue: tile0 (B then A, 8 loads) + tile1 B (4 loads)
    STB(0, 0, 0); STB(0, 1, 0); STA(0, 0, 0); STA(0, 1, 0);
    STB(1, 0, 1); STB(1, 1, 1);
    VM4; BAR;

#pragma unroll 1
    for (int i = 0; i < 8; ++i) {
      const int t1 = 2 * i + 1;
      const int tS2 = (2 * i + 2 < 16) ? 2 * i + 2 : 15;
      const int tS3 = (2 * i + 3 < 16) ? 2 * i + 3 : 15;
      // ph1
      BLD(0); ALD(0, 0); STA(1, 0, t1);
      BAR; LGKM0; SP1; FMQ(0); SP0; BAR;
      // ph2
      ALD(0, 2); STA(1, 1, t1); STB(0, 0, tS2);
      BAR; LGKM0; SP1; FMQ(2); SP0; BAR;
      // ph3
      ALD(0, 4); STB(0, 1, tS2);
      BAR; LGKM0; SP1; FMQ(4); SP0; BAR;
      // ph4
      ALD(0, 6);
      BAR; LGKM0; SP1; FMQ(6); SP0; VM4; BAR;
      // ph5
      BLD(16384); ALD(16384, 0); STA(0, 0, tS2);
      BAR; LGKM0; SP1; FMQ(0); SP0; BAR;
      // ph6
      ALD(16384, 2); STA(0, 1, tS2); STB(1, 0, tS3);
      BAR; LGKM0; SP1; FMQ(2); SP0; BAR;
      // ph7
      ALD(16384, 4); STB(1, 1, tS3);
      BAR; LGKM0; SP1; FMQ(4); SP0; BAR;
      // ph8
      ALD(16384, 6);
      BAR; LGKM0; SP1; FMQ(6); SP0; VM4; BAR;
    }
#undef STA
#undef STB
#undef BLD
#undef ALD
#undef FMQ

    // epilogue: silu(acc + b) * w -> contrib[slot][tok][col]
    const int colb = ct * 256 + wn * 64 + fr;
    float bc[4];
#pragma unroll
    for (int n = 0; n < 4; n++) bc[n] = bias[e * HID + colb + n * 16];
#pragma unroll
    for (int m = 0; m < 8; m++) {
#pragma unroll
      for (int rr = 0; rr < 4; rr++) {
        int r = rt * 256 + wm * 128 + m * 16 + fq * 4 + rr;
        if (r < count) {
          int ent = list[e * CAP + r];
          int tk2 = ent & 0xFFFF;
          int slot = (ent >> 16) & 1;
          float wgt = listw[e * CAP + r];
          ushort* dst = contrib + ((size_t)slot * NTOK + tk2) * HID;
#pragma unroll
          for (int n = 0; n < 4; n++) {
            float v = acc[m][n][rr] + bc[n];
            float sv = v / (1.0f + __expf(-v));
            dst[colb + n * 16] = f2bf(sv * wgt);
          }
        }
      }
    }
  }
}

// ---------------- combine GEMM with fused mix (A = c0+c1, reg-staged) ----------------
__global__ __launch_bounds__(256) void cgemm_kernel(
    const ushort* __restrict__ Cb, const ushort* __restrict__ Bb,
    float* __restrict__ outp) {
  __shared__ ushort As[2][128 * 32];
  __shared__ ushort Bs[2][128 * 32];
  const int tid = threadIdx.x, lane = tid & 63, wave = tid >> 6;
  const int p = blockIdx.x;
  const int cx = p & 7, q = p >> 3, ct = q & 7, rt = ((q >> 3) << 3) | cx;  // rt < 128

  const int cc0 = wave * 2;
  const int rl0 = cc0 * 16 + (lane >> 2);
  const int rl1 = rl0 + 16;
  const int nat8 = (lane & 3) * 8;
  const int swz8 = (((lane & 3) ^ ((lane >> 3) & 3))) * 8;

  const ushort* srcB0 = Bb + (size_t)(ct * 128 + rl0) * HID + swz8;
  const ushort* srcB1 = Bb + (size_t)(ct * 128 + rl1) * HID + swz8;
  const ushort* sA0c0 = Cb + (size_t)(rt * 128 + rl0) * HID + nat8;
  const ushort* sA0c1 = sA0c0 + (size_t)NTOK * HID;
  const ushort* sA1c0 = Cb + (size_t)(rt * 128 + rl1) * HID + nat8;
  const ushort* sA1c1 = sA1c0 + (size_t)NTOK * HID;
  const int wA0 = rl0 * 32 + swz8;
  const int wA1 = rl1 * 32 + swz8;

  f32x4 acc[4][4];
#pragma unroll
  for (int m = 0; m < 4; m++)
#pragma unroll
    for (int n = 0; n < 4; n++) acc[m][n] = (f32x4){0.f, 0.f, 0.f, 0.f};

  const int wm = wave >> 1, wn = wave & 1;
  const int fr = lane & 15, fq = lane >> 4;
  const int sa = (fq ^ ((fr >> 1) & 3)) * 8;

  auto bfadd8 = [](short8 a, short8 b) {
    short8 o;
#pragma unroll
    for (int j = 0; j < 8; j++)
      o[j] = (short)f2bf(bf2f((ushort)a[j]) + bf2f((ushort)b[j]));
    return o;
  };

  gl16(srcB0, &Bs[0][cc0 * 512]);
  gl16(srcB1, &Bs[0][cc0 * 512 + 512]);
  {
    short8 a0 = *reinterpret_cast<const short8*>(sA0c0);
    short8 b0 = *reinterpret_cast<const short8*>(sA0c1);
    short8 a1 = *reinterpret_cast<const short8*>(sA1c0);
    short8 b1 = *reinterpret_cast<const short8*>(sA1c1);
    *reinterpret_cast<short8*>(&As[0][wA0]) = bfadd8(a0, b0);
    *reinterpret_cast<short8*>(&As[0][wA1]) = bfadd8(a1, b1);
  }
  __syncthreads();
  gl16(srcB0 + 32, &Bs[1][cc0 * 512]);
  gl16(srcB1 + 32, &Bs[1][cc0 * 512 + 512]);
  short8 na0 = *reinterpret_cast<const short8*>(sA0c0 + 32);
  short8 nb0 = *reinterpret_cast<const short8*>(sA0c1 + 32);
  short8 na1 = *reinterpret_cast<const short8*>(sA1c0 + 32);
  short8 nb1 = *reinterpret_cast<const short8*>(sA1c1 + 32);

  for (int k0 = 0, t = 0; k0 < HID; k0 += 32, ++t) {
    const ushort* as = As[t & 1];
    const ushort* bs = Bs[t & 1];
    bf16x8 av[4], bv[4];
#pragma unroll
    for (int m = 0; m < 4; m++)
      av[m] = *reinterpret_cast<const bf16x8*>(&as[(wm * 64 + m * 16 + fr) * 32 + sa]);
#pragma unroll
    for (int n = 0; n < 4; n++)
      bv[n] = *reinterpret_cast<const bf16x8*>(&bs[(wn * 64 + n * 16 + fr) * 32 + sa]);
#pragma unroll
    for (int m = 0; m < 4; m++)
#pragma unroll
      for (int n = 0; n < 4; n++)
        acc[m][n] = __builtin_amdgcn_mfma_f32_16x16x32_bf16(av[m], bv[n], acc[m][n], 0, 0, 0);
    if (k0 + 32 < HID) {
      *reinterpret_cast<short8*>(&As[(t + 1) & 1][wA0]) = bfadd8(na0, nb0);
      *reinterpret_cast<short8*>(&As[(t + 1) & 1][wA1]) = bfadd8(na1, nb1);
    }
    __syncthreads();
    if (k0 + 64 < HID) {
      gl16(srcB0 + k0 + 64, &Bs[t & 1][cc0 * 512]);
      gl16(srcB1 + k0 + 64, &Bs[t & 1][cc0 * 512 + 512]);
      na0 = *reinterpret_cast<const short8*>(sA0c0 + k0 + 64);
      nb0 = *reinterpret_cast<const short8*>(sA0c1 + k0 + 64);
      na1 = *reinterpret_cast<const short8*>(sA1c0 + k0 + 64);
      nb1 = *reinterpret_cast<const short8*>(sA1c1 + k0 + 64);
    }
  }

  const int colb = ct * 128 + wn * 64 + fr;
#pragma unroll
  for (int m = 0; m < 4; m++)
#pragma unroll
    for (int rr = 0; rr < 4; rr++) {
      int r = rt * 128 + wm * 64 + m * 16 + fq * 4 + rr;
      float* dst = outp + (size_t)r * HID;
#pragma unroll
      for (int n = 0; n < 4; n++) dst[colb + n * 16] = acc[m][n][rr];
    }
}

extern "C" void kernel_launch(void* const* d_in, const int* in_sizes, int n_in,
                              void* d_out, int out_size, void* d_ws, size_t ws_size,
                              hipStream_t stream) {
  const float* tokens    = (const float*)d_in[0];
  const float* gate_w    = (const float*)d_in[1];
  const float* expert_w  = (const float*)d_in[2];
  const float* expert_b  = (const float*)d_in[3];
  const float* combine_w = (const float*)d_in[4];
  float* outp = (float*)d_out;

  char* p = (char*)d_ws;
  ushort* Xb  = (ushort*)p; p += (size_t)NTOK * HID * 2;        // 33.5 MB
  ushort* Wxb = (ushort*)p; p += (size_t)NEXP * HID * HID * 2;  // 16.8 MB
  ushort* Wcb = (ushort*)p; p += (size_t)HID * HID * 2;         //  2.1 MB
  ushort* ctb = (ushort*)p; p += (size_t)2 * NTOK * HID * 2;    // 67.1 MB
  int*   list = (int*)p;    p += (size_t)NEXP * CAP * 4;
  float* lsw  = (float*)p;  p += (size_t)NEXP * CAP * 4;
  int*   cnts = (int*)p;    p += 256;                           // counts[8] + ticket[1]
  uint32_t* tinfo = (uint32_t*)p; p += (size_t)NTOK * 4;
  float2*   twp   = (float2*)p;   p += (size_t)NTOK * 8;

  zero_kernel<<<1, 64, 0, stream>>>(cnts);
  gate_kernel<<<2048, 256, 0, stream>>>(tokens, gate_w, Xb, tinfo, twp);
  cvt_kernel<<<1024, 256, 0, stream>>>(expert_w, Wxb, NEXP * HID * HID / 4);
  cvt_kernel<<<256, 256, 0, stream>>>(combine_w, Wcb, HID * HID / 4);
  scatter_kernel<<<64, 256, 0, stream>>>(tinfo, twp, list, lsw, cnts);
  egemm_kernel<<<256, 512, 0, stream>>>(Xb, Wxb, expert_b, list, lsw, cnts, ctb);
  cgemm_kernel<<<1024, 256, 0, stream>>>(ctb, Wcb, outp);
}

// Round 7
// 241.545 us; speedup vs baseline: 1.0881x; 1.0881x over previous
//
#include <hip/hip_runtime.h>
#include <stdint.h>

#define HID 1024
#define NEXP 8
#define NTOK 16384
#define CAP 8192

typedef __attribute__((ext_vector_type(8))) __bf16 bf16x8;
typedef __attribute__((ext_vector_type(8))) short short8;
typedef __attribute__((ext_vector_type(4))) float f32x4;

__device__ __forceinline__ ushort f2bf(float f) {
  uint32_t u = __builtin_bit_cast(uint32_t, f);
  u += 0x7FFF + ((u >> 16) & 1);          // round-to-nearest-even
  return (ushort)(u >> 16);
}
__device__ __forceinline__ float bf2f(ushort u) {
  return __builtin_bit_cast(float, (uint32_t)u << 16);
}

__device__ __forceinline__ void gl16(const void* g, void* l) {
  __builtin_amdgcn_global_load_lds((__attribute__((address_space(1))) void*)(g),
                                   (__attribute__((address_space(3))) void*)(l),
                                   16, 0, 0);
}

__global__ void zero_kernel(int* counts) {
  if (threadIdx.x < 16) counts[threadIdx.x] = 0;
}

// ---------------- fused gate + weight conversions (concurrent BW streams) ----------------
// blocks [0,2048): gate (fp32 logits, fused tokens->bf16, no atomics)
// blocks [2048,3072): cvt expert_w -> bf16
// blocks [3072,3328): cvt combine_w -> bf16
__global__ __launch_bounds__(256) void gate_cvt_kernel(
    const float* __restrict__ tokens, const float* __restrict__ gate_w,
    const float* __restrict__ expert_w, const float* __restrict__ combine_w,
    ushort* __restrict__ Xb, ushort* __restrict__ Wxb, ushort* __restrict__ Wcb,
    uint32_t* __restrict__ tinfo, float2* __restrict__ tw) {
  const int b = blockIdx.x;
  if (b >= 2048) {
    const float* src; ushort* dst; int n4, i, stride;
    if (b < 3072) { src = expert_w;  dst = Wxb; n4 = NEXP * HID * HID / 4;
                    i = (b - 2048) * 256 + threadIdx.x; stride = 1024 * 256; }
    else          { src = combine_w; dst = Wcb; n4 = HID * HID / 4;
                    i = (b - 3072) * 256 + threadIdx.x; stride = 256 * 256; }
    for (; i < n4; i += stride) {
      float4 v = reinterpret_cast<const float4*>(src)[i];
      reinterpret_cast<ushort4*>(dst)[i] =
          make_ushort4(f2bf(v.x), f2bf(v.y), f2bf(v.z), f2bf(v.w));
    }
    return;
  }
  const int lane = threadIdx.x & 63;
  const int wave = threadIdx.x >> 6;
  float4 rg[NEXP][4];
#pragma unroll
  for (int e = 0; e < NEXP; e++)
#pragma unroll
    for (int j = 0; j < 4; j++)
      rg[e][j] = reinterpret_cast<const float4*>(gate_w)[e * 256 + j * 64 + lane];

  const int gwid = b * 4 + wave;
  const int nw = 2048 * 4;
  for (int t = gwid; t < NTOK; t += nw) {
    const float4* xr = reinterpret_cast<const float4*>(tokens + (size_t)t * HID);
    float acc[NEXP];
#pragma unroll
    for (int e = 0; e < NEXP; e++) acc[e] = 0.f;
    ushort4 xs[4];
#pragma unroll
    for (int j = 0; j < 4; j++) {
      float4 x = xr[j * 64 + lane];
      xs[j] = make_ushort4(f2bf(x.x), f2bf(x.y), f2bf(x.z), f2bf(x.w));
#pragma unroll
      for (int e = 0; e < NEXP; e++) {
        acc[e] = fmaf(x.x, rg[e][j].x,
                 fmaf(x.y, rg[e][j].y,
                 fmaf(x.z, rg[e][j].z,
                 fmaf(x.w, rg[e][j].w, acc[e]))));
      }
    }
    ushort4* xo = reinterpret_cast<ushort4*>(Xb + (size_t)t * HID);
#pragma unroll
    for (int j = 0; j < 4; j++) xo[j * 64 + lane] = xs[j];
#pragma unroll
    for (int e = 0; e < NEXP; e++) {
#pragma unroll
      for (int s = 32; s > 0; s >>= 1) acc[e] += __shfl_xor(acc[e], s);
    }
    int i1 = 0;
#pragma unroll
    for (int e = 1; e < NEXP; e++) if (acc[e] > acc[i1]) i1 = e;
    int i2 = (i1 == 0) ? 1 : 0;
#pragma unroll
    for (int e = 0; e < NEXP; e++) if (e != i1 && acc[e] > acc[i2]) i2 = e;
    float m = acc[i1];
    float s = 0.f;
#pragma unroll
    for (int e = 0; e < NEXP; e++) s += __expf(acc[e] - m);
    float w1 = 1.f / s;
    float w2 = __expf(acc[i2] - m) / s;
    if (lane == 0) {
      tinfo[t] = (uint32_t)i1 | ((uint32_t)i2 << 8);
      tw[t] = make_float2(w1, w2);
    }
  }
}

// ---------------- scatter: block-aggregated list build ----------------
__global__ __launch_bounds__(256) void scatter_kernel(
    const uint32_t* __restrict__ tinfo, const float2* __restrict__ tw,
    int* __restrict__ list, float* __restrict__ listw, int* __restrict__ counts) {
  __shared__ int lhist[NEXP];
  __shared__ int gbase[NEXP];
  const int tid = threadIdx.x;
  if (tid < NEXP) lhist[tid] = 0;
  __syncthreads();
  const int t = blockIdx.x * 256 + tid;
  uint32_t info = tinfo[t];
  int i1 = info & 0xFF, i2 = (info >> 8) & 0xFF;
  float2 w = tw[t];
  int lr1 = atomicAdd(&lhist[i1], 1);
  int lr2 = atomicAdd(&lhist[i2], 1);
  __syncthreads();
  if (tid < NEXP) gbase[tid] = atomicAdd(&counts[tid], lhist[tid]);
  __syncthreads();
  int p1 = gbase[i1] + lr1;
  if (p1 < CAP) { list[i1 * CAP + p1] = t;           listw[i1 * CAP + p1] = w.x; }
  int p2 = gbase[i2] + lr2;
  if (p2 < CAP) { list[i2 * CAP + p2] = t | 0x10000; listw[i2 * CAP + p2] = w.y; }
}

// ---------------- expert GEMM: r4-proven 128x128x32 counted-vmcnt 2-deep pipeline ----------------
__global__ __launch_bounds__(256) void egemm_kernel(
    const ushort* __restrict__ Ab, const ushort* __restrict__ Bb,
    const float* __restrict__ bias,
    const int* __restrict__ list, const float* __restrict__ listw,
    const int* __restrict__ counts, ushort* __restrict__ contrib) {
  __shared__ ushort As[2][128 * 32];
  __shared__ ushort Bs[2][128 * 32];
  const int tid = threadIdx.x, lane = tid & 63, wave = tid >> 6;
  const int p = blockIdx.x;
  const int cx = p & 7, q = p >> 3, ct = q & 7, g = ((q >> 3) << 3) | cx;
  const int e = g >> 6, rt = g & 63;
  int count = counts[e]; if (count > CAP) count = CAP;
  if (rt * 128 >= count) return;

  const int cc0 = wave * 2;
  const int rl0 = cc0 * 16 + (lane >> 2);
  const int rl1 = rl0 + 16;
  const int swz8 = (((lane & 3) ^ ((lane >> 3) & 3))) * 8;

  int r0 = rt * 128 + rl0, r1 = rt * 128 + rl1;
  int t0 = (r0 < count) ? (list[e * CAP + r0] & 0xFFFF) : 0;
  int t1 = (r1 < count) ? (list[e * CAP + r1] & 0xFFFF) : 0;
  const ushort* srcA0 = Ab + (size_t)t0 * HID + swz8;
  const ushort* srcA1 = Ab + (size_t)t1 * HID + swz8;
  const ushort* Bbase = Bb + (size_t)e * HID * HID;
  const ushort* srcB0 = Bbase + (size_t)(ct * 128 + rl0) * HID + swz8;
  const ushort* srcB1 = Bbase + (size_t)(ct * 128 + rl1) * HID + swz8;

  f32x4 acc[4][4];
#pragma unroll
  for (int m = 0; m < 4; m++)
#pragma unroll
    for (int n = 0; n < 4; n++) acc[m][n] = (f32x4){0.f, 0.f, 0.f, 0.f};

  const int wm = wave >> 1, wn = wave & 1;
  const int fr = lane & 15, fq = lane >> 4;
  const int sa = (fq ^ ((fr >> 1) & 3)) * 8;

#define ESTAGE(K0, BUF) do { \
    gl16(srcA0 + (K0), &As[BUF][cc0 * 512]); \
    gl16(srcA1 + (K0), &As[BUF][cc0 * 512 + 512]); \
    gl16(srcB0 + (K0), &Bs[BUF][cc0 * 512]); \
    gl16(srcB1 + (K0), &Bs[BUF][cc0 * 512 + 512]); \
  } while (0)

  ESTAGE(0, 0);
  ESTAGE(32, 1);
  for (int k0 = 0, t = 0; k0 < HID; k0 += 32, ++t) {
    if (k0 + 32 < HID) asm volatile("s_waitcnt vmcnt(4)" ::: "memory");
    else               asm volatile("s_waitcnt vmcnt(0)" ::: "memory");
    __builtin_amdgcn_s_barrier();
    asm volatile("" ::: "memory");
    const ushort* as = As[t & 1];
    const ushort* bs = Bs[t & 1];
    bf16x8 av[4], bv[4];
#pragma unroll
    for (int m = 0; m < 4; m++)
      av[m] = *reinterpret_cast<const bf16x8*>(&as[(wm * 64 + m * 16 + fr) * 32 + sa]);
#pragma unroll
    for (int n = 0; n < 4; n++)
      bv[n] = *reinterpret_cast<const bf16x8*>(&bs[(wn * 64 + n * 16 + fr) * 32 + sa]);
#pragma unroll
    for (int m = 0; m < 4; m++)
#pragma unroll
      for (int n = 0; n < 4; n++)
        acc[m][n] = __builtin_amdgcn_mfma_f32_16x16x32_bf16(av[m], bv[n], acc[m][n], 0, 0, 0);
    asm volatile("" ::: "memory");
    __builtin_amdgcn_s_barrier();
    if (k0 + 64 < HID) ESTAGE(k0 + 64, t & 1);
  }
#undef ESTAGE

  // epilogue: batched meta loads + rcp-based sigmoid (v_rcp_f32, 1 inst)
  const int colb = ct * 128 + wn * 64 + fr;
  float bc[4];
#pragma unroll
  for (int n = 0; n < 4; n++) bc[n] = bias[e * HID + colb + n * 16];
  const int rb = rt * 128 + wm * 64 + fq * 4;
  int ents[16]; float ws[16];
#pragma unroll
  for (int m = 0; m < 4; m++)
#pragma unroll
    for (int rr = 0; rr < 4; rr++) {
      int r = rb + m * 16 + rr;
      bool v = (r < count);
      ents[m * 4 + rr] = v ? list[e * CAP + r] : -1;
      ws[m * 4 + rr]   = v ? listw[e * CAP + r] : 0.f;
    }
#pragma unroll
  for (int m = 0; m < 4; m++) {
#pragma unroll
    for (int rr = 0; rr < 4; rr++) {
      int ent = ents[m * 4 + rr];
      if (ent >= 0) {
        int tok = ent & 0xFFFF;
        int slot = (ent >> 16) & 1;
        float wgt = ws[m * 4 + rr];
        ushort* dst = contrib + ((size_t)slot * NTOK + tok) * HID;
#pragma unroll
        for (int n = 0; n < 4; n++) {
          float v = acc[m][n][rr] + bc[n];
          float sv = v * __builtin_amdgcn_rcpf(1.0f + __expf(-v));
          dst[colb + n * 16] = f2bf(sv * wgt);
        }
      }
    }
  }
}

// ---------------- combine GEMM with fused mix (A = c0+c1, cvt_pk add) ----------------
__global__ __launch_bounds__(256) void cgemm_kernel(
    const ushort* __restrict__ Cb, const ushort* __restrict__ Bb,
    float* __restrict__ outp) {
  __shared__ ushort As[2][128 * 32];
  __shared__ ushort Bs[2][128 * 32];
  const int tid = threadIdx.x, lane = tid & 63, wave = tid >> 6;
  const int p = blockIdx.x;
  const int cx = p & 7, q = p >> 3, ct = q & 7, rt = ((q >> 3) << 3) | cx;  // rt < 128

  const int cc0 = wave * 2;
  const int rl0 = cc0 * 16 + (lane >> 2);
  const int rl1 = rl0 + 16;
  const int nat8 = (lane & 3) * 8;
  const int swz8 = (((lane & 3) ^ ((lane >> 3) & 3))) * 8;

  const ushort* srcB0 = Bb + (size_t)(ct * 128 + rl0) * HID + swz8;
  const ushort* srcB1 = Bb + (size_t)(ct * 128 + rl1) * HID + swz8;
  const ushort* sA0c0 = Cb + (size_t)(rt * 128 + rl0) * HID + nat8;
  const ushort* sA0c1 = sA0c0 + (size_t)NTOK * HID;
  const ushort* sA1c0 = Cb + (size_t)(rt * 128 + rl1) * HID + nat8;
  const ushort* sA1c1 = sA1c0 + (size_t)NTOK * HID;
  const int wA0 = rl0 * 32 + swz8;
  const int wA1 = rl1 * 32 + swz8;

  f32x4 acc[4][4];
#pragma unroll
  for (int m = 0; m < 4; m++)
#pragma unroll
    for (int n = 0; n < 4; n++) acc[m][n] = (f32x4){0.f, 0.f, 0.f, 0.f};

  const int wm = wave >> 1, wn = wave & 1;
  const int fr = lane & 15, fq = lane >> 4;
  const int sa = (fq ^ ((fr >> 1) & 3)) * 8;

  auto bfadd8 = [](short8 a, short8 b) {
    union { short8 s; uint32_t u[4]; } o;
#pragma unroll
    for (int j = 0; j < 4; j++) {
      float x0 = bf2f((ushort)a[2 * j])     + bf2f((ushort)b[2 * j]);
      float x1 = bf2f((ushort)a[2 * j + 1]) + bf2f((ushort)b[2 * j + 1]);
      uint32_t pk;
      asm("v_cvt_pk_bf16_f32 %0, %1, %2" : "=v"(pk) : "v"(x0), "v"(x1));
      o.u[j] = pk;
    }
    return o.s;
  };

  gl16(srcB0, &Bs[0][cc0 * 512]);
  gl16(srcB1, &Bs[0][cc0 * 512 + 512]);
  {
    short8 a0 = *reinterpret_cast<const short8*>(sA0c0);
    short8 b0 = *reinterpret_cast<const short8*>(sA0c1);
    short8 a1 = *reinterpret_cast<const short8*>(sA1c0);
    short8 b1 = *reinterpret_cast<const short8*>(sA1c1);
    *reinterpret_cast<short8*>(&As[0][wA0]) = bfadd8(a0, b0);
    *reinterpret_cast<short8*>(&As[0][wA1]) = bfadd8(a1, b1);
  }
  __syncthreads();
  gl16(srcB0 + 32, &Bs[1][cc0 * 512]);
  gl16(srcB1 + 32, &Bs[1][cc0 * 512 + 512]);
  short8 na0 = *reinterpret_cast<const short8*>(sA0c0 + 32);
  short8 nb0 = *reinterpret_cast<const short8*>(sA0c1 + 32);
  short8 na1 = *reinterpret_cast<const short8*>(sA1c0 + 32);
  short8 nb1 = *reinterpret_cast<const short8*>(sA1c1 + 32);

  for (int k0 = 0, t = 0; k0 < HID; k0 += 32, ++t) {
    const ushort* as = As[t & 1];
    const ushort* bs = Bs[t & 1];
    bf16x8 av[4], bv[4];
#pragma unroll
    for (int m = 0; m < 4; m++)
      av[m] = *reinterpret_cast<const bf16x8*>(&as[(wm * 64 + m * 16 + fr) * 32 + sa]);
#pragma unroll
    for (int n = 0; n < 4; n++)
      bv[n] = *reinterpret_cast<const bf16x8*>(&bs[(wn * 64 + n * 16 + fr) * 32 + sa]);
#pragma unroll
    for (int m = 0; m < 4; m++)
#pragma unroll
      for (int n = 0; n < 4; n++)
        acc[m][n] = __builtin_amdgcn_mfma_f32_16x16x32_bf16(av[m], bv[n], acc[m][n], 0, 0, 0);
    if (k0 + 32 < HID) {
      *reinterpret_cast<short8*>(&As[(t + 1) & 1][wA0]) = bfadd8(na0, nb0);
      *reinterpret_cast<short8*>(&As[(t + 1) & 1][wA1]) = bfadd8(na1, nb1);
    }
    __syncthreads();
    if (k0 + 64 < HID) {
      gl16(srcB0 + k0 + 64, &Bs[t & 1][cc0 * 512]);
      gl16(srcB1 + k0 + 64, &Bs[t & 1][cc0 * 512 + 512]);
      na0 = *reinterpret_cast<const short8*>(sA0c0 + k0 + 64);
      nb0 = *reinterpret_cast<const short8*>(sA0c1 + k0 + 64);
      na1 = *reinterpret_cast<const short8*>(sA1c0 + k0 + 64);
      nb1 = *reinterpret_cast<const short8*>(sA1c1 + k0 + 64);
    }
  }

  const int colb = ct * 128 + wn * 64 + fr;
#pragma unroll
  for (int m = 0; m < 4; m++)
#pragma unroll
    for (int rr = 0; rr < 4; rr++) {
      int r = rt * 128 + wm * 64 + m * 16 + fq * 4 + rr;
      float* dst = outp + (size_t)r * HID;
#pragma unroll
      for (int n = 0; n < 4; n++) dst[colb + n * 16] = acc[m][n][rr];
    }
}

extern "C" void kernel_launch(void* const* d_in, const int* in_sizes, int n_in,
                              void* d_out, int out_size, void* d_ws, size_t ws_size,
                              hipStream_t stream) {
  const float* tokens    = (const float*)d_in[0];
  const float* gate_w    = (const float*)d_in[1];
  const float* expert_w  = (const float*)d_in[2];
  const float* expert_b  = (const float*)d_in[3];
  const float* combine_w = (const float*)d_in[4];
  float* outp = (float*)d_out;

  char* p = (char*)d_ws;
  ushort* Xb  = (ushort*)p; p += (size_t)NTOK * HID * 2;        // 33.5 MB
  ushort* Wxb = (ushort*)p; p += (size_t)NEXP * HID * HID * 2;  // 16.8 MB
  ushort* Wcb = (ushort*)p; p += (size_t)HID * HID * 2;         //  2.1 MB
  ushort* ctb = (ushort*)p; p += (size_t)2 * NTOK * HID * 2;    // 67.1 MB
  int*   list = (int*)p;    p += (size_t)NEXP * CAP * 4;
  float* lsw  = (float*)p;  p += (size_t)NEXP * CAP * 4;
  int*   cnts = (int*)p;    p += 256;
  uint32_t* tinfo = (uint32_t*)p; p += (size_t)NTOK * 4;
  float2*   twp   = (float2*)p;   p += (size_t)NTOK * 8;

  zero_kernel<<<1, 64, 0, stream>>>(cnts);
  gate_cvt_kernel<<<3328, 256, 0, stream>>>(tokens, gate_w, expert_w, combine_w,
                                            Xb, Wxb, Wcb, tinfo, twp);
  scatter_kernel<<<64, 256, 0, stream>>>(tinfo, twp, list, lsw, cnts);
  egemm_kernel<<<4096, 256, 0, stream>>>(Xb, Wxb, expert_b, list, lsw, cnts, ctb);
  cgemm_kernel<<<1024, 256, 0, stream>>>(ctb, Wcb, outp);
}

// Round 8
// 222.310 us; speedup vs baseline: 1.1823x; 1.0865x over previous
//
#include <hip/hip_runtime.h>
#include <stdint.h>

#define HID 1024
#define NEXP 8
#define NTOK 16384
#define CAP 8192

typedef __attribute__((ext_vector_type(8))) __bf16 bf16x8;
typedef __attribute__((ext_vector_type(8))) short short8;
typedef __attribute__((ext_vector_type(4))) float f32x4;

__device__ __forceinline__ ushort f2bf(float f) {
  uint32_t u = __builtin_bit_cast(uint32_t, f);
  u += 0x7FFF + ((u >> 16) & 1);          // round-to-nearest-even
  return (ushort)(u >> 16);
}
__device__ __forceinline__ float bf2f(ushort u) {
  return __builtin_bit_cast(float, (uint32_t)u << 16);
}

__device__ __forceinline__ void gl16(const void* g, void* l) {
  __builtin_amdgcn_global_load_lds((__attribute__((address_space(1))) void*)(g),
                                   (__attribute__((address_space(3))) void*)(l),
                                   16, 0, 0);
}

__global__ void zero_kernel(int* counts) {
  if (threadIdx.x < 16) counts[threadIdx.x] = 0;
}

// ---------------- fused gate + weight conversions (concurrent BW streams) ----------------
__global__ __launch_bounds__(256) void gate_cvt_kernel(
    const float* __restrict__ tokens, const float* __restrict__ gate_w,
    const float* __restrict__ expert_w, const float* __restrict__ combine_w,
    ushort* __restrict__ Xb, ushort* __restrict__ Wxb, ushort* __restrict__ Wcb,
    uint32_t* __restrict__ tinfo, float2* __restrict__ tw) {
  const int b = blockIdx.x;
  if (b >= 2048) {
    const float* src; ushort* dst; int n4, i, stride;
    if (b < 3072) { src = expert_w;  dst = Wxb; n4 = NEXP * HID * HID / 4;
                    i = (b - 2048) * 256 + threadIdx.x; stride = 1024 * 256; }
    else          { src = combine_w; dst = Wcb; n4 = HID * HID / 4;
                    i = (b - 3072) * 256 + threadIdx.x; stride = 256 * 256; }
    for (; i < n4; i += stride) {
      float4 v = reinterpret_cast<const float4*>(src)[i];
      reinterpret_cast<ushort4*>(dst)[i] =
          make_ushort4(f2bf(v.x), f2bf(v.y), f2bf(v.z), f2bf(v.w));
    }
    return;
  }
  const int lane = threadIdx.x & 63;
  const int wave = threadIdx.x >> 6;
  float4 rg[NEXP][4];
#pragma unroll
  for (int e = 0; e < NEXP; e++)
#pragma unroll
    for (int j = 0; j < 4; j++)
      rg[e][j] = reinterpret_cast<const float4*>(gate_w)[e * 256 + j * 64 + lane];

  const int gwid = b * 4 + wave;
  const int nw = 2048 * 4;
  for (int t = gwid; t < NTOK; t += nw) {
    const float4* xr = reinterpret_cast<const float4*>(tokens + (size_t)t * HID);
    float acc[NEXP];
#pragma unroll
    for (int e = 0; e < NEXP; e++) acc[e] = 0.f;
    ushort4 xs[4];
#pragma unroll
    for (int j = 0; j < 4; j++) {
      float4 x = xr[j * 64 + lane];
      xs[j] = make_ushort4(f2bf(x.x), f2bf(x.y), f2bf(x.z), f2bf(x.w));
#pragma unroll
      for (int e = 0; e < NEXP; e++) {
        acc[e] = fmaf(x.x, rg[e][j].x,
                 fmaf(x.y, rg[e][j].y,
                 fmaf(x.z, rg[e][j].z,
                 fmaf(x.w, rg[e][j].w, acc[e]))));
      }
    }
    ushort4* xo = reinterpret_cast<ushort4*>(Xb + (size_t)t * HID);
#pragma unroll
    for (int j = 0; j < 4; j++) xo[j * 64 + lane] = xs[j];
#pragma unroll
    for (int e = 0; e < NEXP; e++) {
#pragma unroll
      for (int s = 32; s > 0; s >>= 1) acc[e] += __shfl_xor(acc[e], s);
    }
    int i1 = 0;
#pragma unroll
    for (int e = 1; e < NEXP; e++) if (acc[e] > acc[i1]) i1 = e;
    int i2 = (i1 == 0) ? 1 : 0;
#pragma unroll
    for (int e = 0; e < NEXP; e++) if (e != i1 && acc[e] > acc[i2]) i2 = e;
    float m = acc[i1];
    float s = 0.f;
#pragma unroll
    for (int e = 0; e < NEXP; e++) s += __expf(acc[e] - m);
    float w1 = 1.f / s;
    float w2 = __expf(acc[i2] - m) / s;
    if (lane == 0) {
      tinfo[t] = (uint32_t)i1 | ((uint32_t)i2 << 8);
      tw[t] = make_float2(w1, w2);
    }
  }
}

// ---------------- scatter: block-aggregated list build ----------------
__global__ __launch_bounds__(256) void scatter_kernel(
    const uint32_t* __restrict__ tinfo, const float2* __restrict__ tw,
    int* __restrict__ list, float* __restrict__ listw, int* __restrict__ counts) {
  __shared__ int lhist[NEXP];
  __shared__ int gbase[NEXP];
  const int tid = threadIdx.x;
  if (tid < NEXP) lhist[tid] = 0;
  __syncthreads();
  const int t = blockIdx.x * 256 + tid;
  uint32_t info = tinfo[t];
  int i1 = info & 0xFF, i2 = (info >> 8) & 0xFF;
  float2 w = tw[t];
  int lr1 = atomicAdd(&lhist[i1], 1);
  int lr2 = atomicAdd(&lhist[i2], 1);
  __syncthreads();
  if (tid < NEXP) gbase[tid] = atomicAdd(&counts[tid], lhist[tid]);
  __syncthreads();
  int p1 = gbase[i1] + lr1;
  if (p1 < CAP) { list[i1 * CAP + p1] = t;           listw[i1 * CAP + p1] = w.x; }
  int p2 = gbase[i2] + lr2;
  if (p2 < CAP) { list[i2 * CAP + p2] = t | 0x10000; listw[i2 * CAP + p2] = w.y; }
}

// shared fragment-read + 16-MFMA macros (names av0..3/bv0..3/acc fixed)
#define LDFRAGS(AB, BB) \
    bf16x8 av0 = *(const bf16x8*)(AB);          bf16x8 av1 = *(const bf16x8*)((AB) + 512); \
    bf16x8 av2 = *(const bf16x8*)((AB) + 1024); bf16x8 av3 = *(const bf16x8*)((AB) + 1536); \
    bf16x8 bv0 = *(const bf16x8*)(BB);          bf16x8 bv1 = *(const bf16x8*)((BB) + 512); \
    bf16x8 bv2 = *(const bf16x8*)((BB) + 1024); bf16x8 bv3 = *(const bf16x8*)((BB) + 1536);
#define MF16 do { \
    acc[0][0] = __builtin_amdgcn_mfma_f32_16x16x32_bf16(av0, bv0, acc[0][0], 0, 0, 0); \
    acc[0][1] = __builtin_amdgcn_mfma_f32_16x16x32_bf16(av0, bv1, acc[0][1], 0, 0, 0); \
    acc[0][2] = __builtin_amdgcn_mfma_f32_16x16x32_bf16(av0, bv2, acc[0][2], 0, 0, 0); \
    acc[0][3] = __builtin_amdgcn_mfma_f32_16x16x32_bf16(av0, bv3, acc[0][3], 0, 0, 0); \
    acc[1][0] = __builtin_amdgcn_mfma_f32_16x16x32_bf16(av1, bv0, acc[1][0], 0, 0, 0); \
    acc[1][1] = __builtin_amdgcn_mfma_f32_16x16x32_bf16(av1, bv1, acc[1][1], 0, 0, 0); \
    acc[1][2] = __builtin_amdgcn_mfma_f32_16x16x32_bf16(av1, bv2, acc[1][2], 0, 0, 0); \
    acc[1][3] = __builtin_amdgcn_mfma_f32_16x16x32_bf16(av1, bv3, acc[1][3], 0, 0, 0); \
    acc[2][0] = __builtin_amdgcn_mfma_f32_16x16x32_bf16(av2, bv0, acc[2][0], 0, 0, 0); \
    acc[2][1] = __builtin_amdgcn_mfma_f32_16x16x32_bf16(av2, bv1, acc[2][1], 0, 0, 0); \
    acc[2][2] = __builtin_amdgcn_mfma_f32_16x16x32_bf16(av2, bv2, acc[2][2], 0, 0, 0); \
    acc[2][3] = __builtin_amdgcn_mfma_f32_16x16x32_bf16(av2, bv3, acc[2][3], 0, 0, 0); \
    acc[3][0] = __builtin_amdgcn_mfma_f32_16x16x32_bf16(av3, bv0, acc[3][0], 0, 0, 0); \
    acc[3][1] = __builtin_amdgcn_mfma_f32_16x16x32_bf16(av3, bv1, acc[3][1], 0, 0, 0); \
    acc[3][2] = __builtin_amdgcn_mfma_f32_16x16x32_bf16(av3, bv2, acc[3][2], 0, 0, 0); \
    acc[3][3] = __builtin_amdgcn_mfma_f32_16x16x32_bf16(av3, bv3, acc[3][3], 0, 0, 0); } while (0)

// ---------------- expert GEMM: r4 schedule, fully unrolled K (static parity) ----------------
__global__ __launch_bounds__(256) void egemm_kernel(
    const ushort* __restrict__ Ab, const ushort* __restrict__ Bb,
    const float* __restrict__ bias,
    const int* __restrict__ list, const float* __restrict__ listw,
    const int* __restrict__ counts, ushort* __restrict__ contrib) {
  __shared__ ushort As[2][128 * 32];
  __shared__ ushort Bs[2][128 * 32];
  const int tid = threadIdx.x, lane = tid & 63, wave = tid >> 6;
  const int p = blockIdx.x;
  const int cx = p & 7, q = p >> 3, ct = q & 7, g = ((q >> 3) << 3) | cx;
  const int e = g >> 6, rt = g & 63;
  int count = counts[e]; if (count > CAP) count = CAP;
  if (rt * 128 >= count) return;

  const int cc0 = wave * 2;
  const int rl0 = cc0 * 16 + (lane >> 2);
  const int rl1 = rl0 + 16;
  const int swz8 = (((lane & 3) ^ ((lane >> 3) & 3))) * 8;

  int r0 = rt * 128 + rl0, r1 = rt * 128 + rl1;
  int t0 = (r0 < count) ? (list[e * CAP + r0] & 0xFFFF) : 0;
  int t1 = (r1 < count) ? (list[e * CAP + r1] & 0xFFFF) : 0;
  const ushort* srcA0 = Ab + (size_t)t0 * HID + swz8;
  const ushort* srcA1 = Ab + (size_t)t1 * HID + swz8;
  const ushort* Bbase = Bb + (size_t)e * HID * HID;
  const ushort* srcB0 = Bbase + (size_t)(ct * 128 + rl0) * HID + swz8;
  const ushort* srcB1 = Bbase + (size_t)(ct * 128 + rl1) * HID + swz8;

  f32x4 acc[4][4];
#pragma unroll
  for (int m = 0; m < 4; m++)
#pragma unroll
    for (int n = 0; n < 4; n++) acc[m][n] = (f32x4){0.f, 0.f, 0.f, 0.f};

  const int wm = wave >> 1, wn = wave & 1;
  const int fr = lane & 15, fq = lane >> 4;
  const int sa = (fq ^ ((fr >> 1) & 3)) * 8;

  ushort* dA0 = &As[0][cc0 * 512];
  ushort* dA1 = &As[1][cc0 * 512];
  ushort* dB0 = &Bs[0][cc0 * 512];
  ushort* dB1 = &Bs[1][cc0 * 512];
  const ushort* aR0 = &As[0][(wm * 64 + fr) * 32 + sa];
  const ushort* aR1 = &As[1][(wm * 64 + fr) * 32 + sa];
  const ushort* bR0 = &Bs[0][(wn * 64 + fr) * 32 + sa];
  const ushort* bR1 = &Bs[1][(wn * 64 + fr) * 32 + sa];

#define ESTG(K0, B) do { \
    gl16(srcA0 + (K0), (B) ? dA1 : dA0); gl16(srcA1 + (K0), ((B) ? dA1 : dA0) + 512); \
    gl16(srcB0 + (K0), (B) ? dB1 : dB0); gl16(srcB1 + (K0), ((B) ? dB1 : dB0) + 512); } while (0)
#define EKS(T) do { \
    if ((T) < 31) asm volatile("s_waitcnt vmcnt(4)" ::: "memory"); \
    else          asm volatile("s_waitcnt vmcnt(0)" ::: "memory"); \
    __builtin_amdgcn_s_barrier(); \
    asm volatile("" ::: "memory"); \
    LDFRAGS(((T) & 1) ? aR1 : aR0, ((T) & 1) ? bR1 : bR0); \
    MF16; \
    asm volatile("" ::: "memory"); \
    __builtin_amdgcn_s_barrier(); \
    if ((T) + 2 < 32) ESTG(((T) + 2) * 32, (T) & 1); } while (0)

  ESTG(0, 0); ESTG(32, 1);
  EKS(0);  EKS(1);  EKS(2);  EKS(3);  EKS(4);  EKS(5);  EKS(6);  EKS(7);
  EKS(8);  EKS(9);  EKS(10); EKS(11); EKS(12); EKS(13); EKS(14); EKS(15);
  EKS(16); EKS(17); EKS(18); EKS(19); EKS(20); EKS(21); EKS(22); EKS(23);
  EKS(24); EKS(25); EKS(26); EKS(27); EKS(28); EKS(29); EKS(30); EKS(31);
#undef ESTG
#undef EKS

  // epilogue: batched meta loads + rcp-based sigmoid
  const int colb = ct * 128 + wn * 64 + fr;
  float bc[4];
#pragma unroll
  for (int n = 0; n < 4; n++) bc[n] = bias[e * HID + colb + n * 16];
  const int rb = rt * 128 + wm * 64 + fq * 4;
  int ents[16]; float ws[16];
#pragma unroll
  for (int m = 0; m < 4; m++)
#pragma unroll
    for (int rr = 0; rr < 4; rr++) {
      int r = rb + m * 16 + rr;
      bool v = (r < count);
      ents[m * 4 + rr] = v ? list[e * CAP + r] : -1;
      ws[m * 4 + rr]   = v ? listw[e * CAP + r] : 0.f;
    }
#pragma unroll
  for (int m = 0; m < 4; m++) {
#pragma unroll
    for (int rr = 0; rr < 4; rr++) {
      int ent = ents[m * 4 + rr];
      if (ent >= 0) {
        int tok = ent & 0xFFFF;
        int slot = (ent >> 16) & 1;
        float wgt = ws[m * 4 + rr];
        ushort* dst = contrib + ((size_t)slot * NTOK + tok) * HID;
#pragma unroll
        for (int n = 0; n < 4; n++) {
          float v = acc[m][n][rr] + bc[n];
          float sv = v * __builtin_amdgcn_rcpf(1.0f + __expf(-v));
          dst[colb + n * 16] = f2bf(sv * wgt);
        }
      }
    }
  }
}

// ---------------- combine GEMM with fused mix, fully unrolled K ----------------
__global__ __launch_bounds__(256) void cgemm_kernel(
    const ushort* __restrict__ Cb, const ushort* __restrict__ Bb,
    float* __restrict__ outp) {
  __shared__ ushort As[2][128 * 32];
  __shared__ ushort Bs[2][128 * 32];
  const int tid = threadIdx.x, lane = tid & 63, wave = tid >> 6;
  const int p = blockIdx.x;
  const int cx = p & 7, q = p >> 3, ct = q & 7, rt = ((q >> 3) << 3) | cx;  // rt < 128

  const int cc0 = wave * 2;
  const int rl0 = cc0 * 16 + (lane >> 2);
  const int rl1 = rl0 + 16;
  const int nat8 = (lane & 3) * 8;
  const int swz8 = (((lane & 3) ^ ((lane >> 3) & 3))) * 8;

  const ushort* srcB0 = Bb + (size_t)(ct * 128 + rl0) * HID + swz8;
  const ushort* srcB1 = Bb + (size_t)(ct * 128 + rl1) * HID + swz8;
  const ushort* sA0c0 = Cb + (size_t)(rt * 128 + rl0) * HID + nat8;
  const ushort* sA0c1 = sA0c0 + (size_t)NTOK * HID;
  const ushort* sA1c0 = Cb + (size_t)(rt * 128 + rl1) * HID + nat8;
  const ushort* sA1c1 = sA1c0 + (size_t)NTOK * HID;

  f32x4 acc[4][4];
#pragma unroll
  for (int m = 0; m < 4; m++)
#pragma unroll
    for (int n = 0; n < 4; n++) acc[m][n] = (f32x4){0.f, 0.f, 0.f, 0.f};

  const int wm = wave >> 1, wn = wave & 1;
  const int fr = lane & 15, fq = lane >> 4;
  const int sa = (fq ^ ((fr >> 1) & 3)) * 8;

  ushort* dB0 = &Bs[0][cc0 * 512];
  ushort* dB1 = &Bs[1][cc0 * 512];
  const int wA0 = rl0 * 32 + swz8;
  const int wA1 = rl1 * 32 + swz8;
  ushort* wAd0a = &As[0][wA0]; ushort* wAd0b = &As[0][wA1];
  ushort* wAd1a = &As[1][wA0]; ushort* wAd1b = &As[1][wA1];
  const ushort* aR0 = &As[0][(wm * 64 + fr) * 32 + sa];
  const ushort* aR1 = &As[1][(wm * 64 + fr) * 32 + sa];
  const ushort* bR0 = &Bs[0][(wn * 64 + fr) * 32 + sa];
  const ushort* bR1 = &Bs[1][(wn * 64 + fr) * 32 + sa];

  auto bfadd8 = [](short8 a, short8 b) {
    union { short8 s; uint32_t u[4]; } o;
#pragma unroll
    for (int j = 0; j < 4; j++) {
      float x0 = bf2f((ushort)a[2 * j])     + bf2f((ushort)b[2 * j]);
      float x1 = bf2f((ushort)a[2 * j + 1]) + bf2f((ushort)b[2 * j + 1]);
      uint32_t pk;
      asm("v_cvt_pk_bf16_f32 %0, %1, %2" : "=v"(pk) : "v"(x0), "v"(x1));
      o.u[j] = pk;
    }
    return o.s;
  };

  short8 na0, nb0, na1, nb1;
  // prologue: B(0) stage; A(0) regs; B(1) stage; A(0) LDS write; A(1) regs
  gl16(srcB0, dB0); gl16(srcB1, dB0 + 512);
  na0 = *(const short8*)(sA0c0); nb0 = *(const short8*)(sA0c1);
  na1 = *(const short8*)(sA1c0); nb1 = *(const short8*)(sA1c1);
  gl16(srcB0 + 32, dB1); gl16(srcB1 + 32, dB1 + 512);
  *(short8*)wAd0a = bfadd8(na0, nb0);
  *(short8*)wAd0b = bfadd8(na1, nb1);
  na0 = *(const short8*)(sA0c0 + 32); nb0 = *(const short8*)(sA0c1 + 32);
  na1 = *(const short8*)(sA1c0 + 32); nb1 = *(const short8*)(sA1c1 + 32);
  asm volatile("s_waitcnt lgkmcnt(0)" ::: "memory");
  __builtin_amdgcn_s_barrier();

#define CKS(T) do { \
    LDFRAGS(((T) & 1) ? aR1 : aR0, ((T) & 1) ? bR1 : bR0); \
    MF16; \
    if ((T) + 1 < 32) { \
      short8 w0 = bfadd8(na0, nb0); \
      short8 w1 = bfadd8(na1, nb1); \
      *(short8*)((((T) + 1) & 1) ? wAd1a : wAd0a) = w0; \
      *(short8*)((((T) + 1) & 1) ? wAd1b : wAd0b) = w1; \
    } \
    asm volatile("s_waitcnt lgkmcnt(0)" ::: "memory"); \
    __builtin_amdgcn_s_barrier(); \
    if ((T) + 2 < 32) { \
      gl16(srcB0 + ((T) + 2) * 32, ((T) & 1) ? dB1 : dB0); \
      gl16(srcB1 + ((T) + 2) * 32, (((T) & 1) ? dB1 : dB0) + 512); \
      na0 = *(const short8*)(sA0c0 + ((T) + 2) * 32); \
      nb0 = *(const short8*)(sA0c1 + ((T) + 2) * 32); \
      na1 = *(const short8*)(sA1c0 + ((T) + 2) * 32); \
      nb1 = *(const short8*)(sA1c1 + ((T) + 2) * 32); \
    } } while (0)

  CKS(0);  CKS(1);  CKS(2);  CKS(3);  CKS(4);  CKS(5);  CKS(6);  CKS(7);
  CKS(8);  CKS(9);  CKS(10); CKS(11); CKS(12); CKS(13); CKS(14); CKS(15);
  CKS(16); CKS(17); CKS(18); CKS(19); CKS(20); CKS(21); CKS(22); CKS(23);
  CKS(24); CKS(25); CKS(26); CKS(27); CKS(28); CKS(29); CKS(30); CKS(31);
#undef CKS

  const int colb = ct * 128 + wn * 64 + fr;
#pragma unroll
  for (int m = 0; m < 4; m++)
#pragma unroll
    for (int rr = 0; rr < 4; rr++) {
      int r = rt * 128 + wm * 64 + m * 16 + fq * 4 + rr;
      float* dst = outp + (size_t)r * HID;
#pragma unroll
      for (int n = 0; n < 4; n++) dst[colb + n * 16] = acc[m][n][rr];
    }
}

extern "C" void kernel_launch(void* const* d_in, const int* in_sizes, int n_in,
                              void* d_out, int out_size, void* d_ws, size_t ws_size,
                              hipStream_t stream) {
  const float* tokens    = (const float*)d_in[0];
  const float* gate_w    = (const float*)d_in[1];
  const float* expert_w  = (const float*)d_in[2];
  const float* expert_b  = (const float*)d_in[3];
  const float* combine_w = (const float*)d_in[4];
  float* outp = (float*)d_out;

  char* p = (char*)d_ws;
  ushort* Xb  = (ushort*)p; p += (size_t)NTOK * HID * 2;        // 33.5 MB
  ushort* Wxb = (ushort*)p; p += (size_t)NEXP * HID * HID * 2;  // 16.8 MB
  ushort* Wcb = (ushort*)p; p += (size_t)HID * HID * 2;         //  2.1 MB
  ushort* ctb = (ushort*)p; p += (size_t)2 * NTOK * HID * 2;    // 67.1 MB
  int*   list = (int*)p;    p += (size_t)NEXP * CAP * 4;
  float* lsw  = (float*)p;  p += (size_t)NEXP * CAP * 4;
  int*   cnts = (int*)p;    p += 256;
  uint32_t* tinfo = (uint32_t*)p; p += (size_t)NTOK * 4;
  float2*   twp   = (float2*)p;   p += (size_t)NTOK * 8;

  zero_kernel<<<1, 64, 0, stream>>>(cnts);
  gate_cvt_kernel<<<3328, 256, 0, stream>>>(tokens, gate_w, expert_w, combine_w,
                                            Xb, Wxb, Wcb, tinfo, twp);
  scatter_kernel<<<64, 256, 0, stream>>>(tinfo, twp, list, lsw, cnts);
  egemm_kernel<<<4096, 256, 0, stream>>>(Xb, Wxb, expert_b, list, lsw, cnts, ctb);
  cgemm_kernel<<<1024, 256, 0, stream>>>(ctb, Wcb, outp);
}

// Round 9
// 218.346 us; speedup vs baseline: 1.2037x; 1.0182x over previous
//
#include <hip/hip_runtime.h>
#include <stdint.h>

#define HID 1024
#define NEXP 8
#define NTOK 16384
#define CAP 8192

typedef __attribute__((ext_vector_type(8))) __bf16 bf16x8;
typedef __attribute__((ext_vector_type(8))) short short8;
typedef __attribute__((ext_vector_type(4))) float f32x4;

__device__ __forceinline__ ushort f2bf(float f) {
  uint32_t u = __builtin_bit_cast(uint32_t, f);
  u += 0x7FFF + ((u >> 16) & 1);          // round-to-nearest-even
  return (ushort)(u >> 16);
}
__device__ __forceinline__ float bf2f(ushort u) {
  return __builtin_bit_cast(float, (uint32_t)u << 16);
}

__device__ __forceinline__ void gl16(const void* g, void* l) {
  __builtin_amdgcn_global_load_lds((__attribute__((address_space(1))) void*)(g),
                                   (__attribute__((address_space(3))) void*)(l),
                                   16, 0, 0);
}

__global__ void zero_kernel(int* counts) {
  if (threadIdx.x < 16) counts[threadIdx.x] = 0;
}

// ---------------- fused gate + weight conversions (concurrent BW streams) ----------------
__global__ __launch_bounds__(256) void gate_cvt_kernel(
    const float* __restrict__ tokens, const float* __restrict__ gate_w,
    const float* __restrict__ expert_w, const float* __restrict__ combine_w,
    ushort* __restrict__ Xb, ushort* __restrict__ Wxb, ushort* __restrict__ Wcb,
    uint32_t* __restrict__ tinfo, float2* __restrict__ tw) {
  const int b = blockIdx.x;
  if (b >= 2048) {
    const float* src; ushort* dst; int n4, i, stride;
    if (b < 3072) { src = expert_w;  dst = Wxb; n4 = NEXP * HID * HID / 4;
                    i = (b - 2048) * 256 + threadIdx.x; stride = 1024 * 256; }
    else          { src = combine_w; dst = Wcb; n4 = HID * HID / 4;
                    i = (b - 3072) * 256 + threadIdx.x; stride = 256 * 256; }
    for (; i < n4; i += stride) {
      float4 v = reinterpret_cast<const float4*>(src)[i];
      reinterpret_cast<ushort4*>(dst)[i] =
          make_ushort4(f2bf(v.x), f2bf(v.y), f2bf(v.z), f2bf(v.w));
    }
    return;
  }
  const int lane = threadIdx.x & 63;
  const int wave = threadIdx.x >> 6;
  float4 rg[NEXP][4];
#pragma unroll
  for (int e = 0; e < NEXP; e++)
#pragma unroll
    for (int j = 0; j < 4; j++)
      rg[e][j] = reinterpret_cast<const float4*>(gate_w)[e * 256 + j * 64 + lane];

  const int gwid = b * 4 + wave;
  const int nw = 2048 * 4;
  for (int t = gwid; t < NTOK; t += nw) {
    const float4* xr = reinterpret_cast<const float4*>(tokens + (size_t)t * HID);
    float acc[NEXP];
#pragma unroll
    for (int e = 0; e < NEXP; e++) acc[e] = 0.f;
    ushort4 xs[4];
#pragma unroll
    for (int j = 0; j < 4; j++) {
      float4 x = xr[j * 64 + lane];
      xs[j] = make_ushort4(f2bf(x.x), f2bf(x.y), f2bf(x.z), f2bf(x.w));
#pragma unroll
      for (int e = 0; e < NEXP; e++) {
        acc[e] = fmaf(x.x, rg[e][j].x,
                 fmaf(x.y, rg[e][j].y,
                 fmaf(x.z, rg[e][j].z,
                 fmaf(x.w, rg[e][j].w, acc[e]))));
      }
    }
    ushort4* xo = reinterpret_cast<ushort4*>(Xb + (size_t)t * HID);
#pragma unroll
    for (int j = 0; j < 4; j++) xo[j * 64 + lane] = xs[j];
#pragma unroll
    for (int e = 0; e < NEXP; e++) {
#pragma unroll
      for (int s = 32; s > 0; s >>= 1) acc[e] += __shfl_xor(acc[e], s);
    }
    int i1 = 0;
#pragma unroll
    for (int e = 1; e < NEXP; e++) if (acc[e] > acc[i1]) i1 = e;
    int i2 = (i1 == 0) ? 1 : 0;
#pragma unroll
    for (int e = 0; e < NEXP; e++) if (e != i1 && acc[e] > acc[i2]) i2 = e;
    float m = acc[i1];
    float s = 0.f;
#pragma unroll
    for (int e = 0; e < NEXP; e++) s += __expf(acc[e] - m);
    float w1 = 1.f / s;
    float w2 = __expf(acc[i2] - m) / s;
    if (lane == 0) {
      tinfo[t] = (uint32_t)i1 | ((uint32_t)i2 << 8);
      tw[t] = make_float2(w1, w2);
    }
  }
}

// ---------------- scatter: block-aggregated list build ----------------
__global__ __launch_bounds__(256) void scatter_kernel(
    const uint32_t* __restrict__ tinfo, const float2* __restrict__ tw,
    int* __restrict__ list, float* __restrict__ listw, int* __restrict__ counts) {
  __shared__ int lhist[NEXP];
  __shared__ int gbase[NEXP];
  const int tid = threadIdx.x;
  if (tid < NEXP) lhist[tid] = 0;
  __syncthreads();
  const int t = blockIdx.x * 256 + tid;
  uint32_t info = tinfo[t];
  int i1 = info & 0xFF, i2 = (info >> 8) & 0xFF;
  float2 w = tw[t];
  int lr1 = atomicAdd(&lhist[i1], 1);
  int lr2 = atomicAdd(&lhist[i2], 1);
  __syncthreads();
  if (tid < NEXP) gbase[tid] = atomicAdd(&counts[tid], lhist[tid]);
  __syncthreads();
  int p1 = gbase[i1] + lr1;
  if (p1 < CAP) { list[i1 * CAP + p1] = t;           listw[i1 * CAP + p1] = w.x; }
  int p2 = gbase[i2] + lr2;
  if (p2 < CAP) { list[i2 * CAP + p2] = t | 0x10000; listw[i2 * CAP + p2] = w.y; }
}

// shared fragment-read + 16-MFMA macros (names av0..3/bv0..3/acc fixed)
#define LDFRAGS(AB, BB) \
    bf16x8 av0 = *(const bf16x8*)(AB);          bf16x8 av1 = *(const bf16x8*)((AB) + 512); \
    bf16x8 av2 = *(const bf16x8*)((AB) + 1024); bf16x8 av3 = *(const bf16x8*)((AB) + 1536); \
    bf16x8 bv0 = *(const bf16x8*)(BB);          bf16x8 bv1 = *(const bf16x8*)((BB) + 512); \
    bf16x8 bv2 = *(const bf16x8*)((BB) + 1024); bf16x8 bv3 = *(const bf16x8*)((BB) + 1536);
#define MF16 do { \
    acc[0][0] = __builtin_amdgcn_mfma_f32_16x16x32_bf16(av0, bv0, acc[0][0], 0, 0, 0); \
    acc[0][1] = __builtin_amdgcn_mfma_f32_16x16x32_bf16(av0, bv1, acc[0][1], 0, 0, 0); \
    acc[0][2] = __builtin_amdgcn_mfma_f32_16x16x32_bf16(av0, bv2, acc[0][2], 0, 0, 0); \
    acc[0][3] = __builtin_amdgcn_mfma_f32_16x16x32_bf16(av0, bv3, acc[0][3], 0, 0, 0); \
    acc[1][0] = __builtin_amdgcn_mfma_f32_16x16x32_bf16(av1, bv0, acc[1][0], 0, 0, 0); \
    acc[1][1] = __builtin_amdgcn_mfma_f32_16x16x32_bf16(av1, bv1, acc[1][1], 0, 0, 0); \
    acc[1][2] = __builtin_amdgcn_mfma_f32_16x16x32_bf16(av1, bv2, acc[1][2], 0, 0, 0); \
    acc[1][3] = __builtin_amdgcn_mfma_f32_16x16x32_bf16(av1, bv3, acc[1][3], 0, 0, 0); \
    acc[2][0] = __builtin_amdgcn_mfma_f32_16x16x32_bf16(av2, bv0, acc[2][0], 0, 0, 0); \
    acc[2][1] = __builtin_amdgcn_mfma_f32_16x16x32_bf16(av2, bv1, acc[2][1], 0, 0, 0); \
    acc[2][2] = __builtin_amdgcn_mfma_f32_16x16x32_bf16(av2, bv2, acc[2][2], 0, 0, 0); \
    acc[2][3] = __builtin_amdgcn_mfma_f32_16x16x32_bf16(av2, bv3, acc[2][3], 0, 0, 0); \
    acc[3][0] = __builtin_amdgcn_mfma_f32_16x16x32_bf16(av3, bv0, acc[3][0], 0, 0, 0); \
    acc[3][1] = __builtin_amdgcn_mfma_f32_16x16x32_bf16(av3, bv1, acc[3][1], 0, 0, 0); \
    acc[3][2] = __builtin_amdgcn_mfma_f32_16x16x32_bf16(av3, bv2, acc[3][2], 0, 0, 0); \
    acc[3][3] = __builtin_amdgcn_mfma_f32_16x16x32_bf16(av3, bv3, acc[3][3], 0, 0, 0); } while (0)

// ---------------- expert GEMM: 3-buffer rotation, ONE barrier per K-step ----------------
// Staging tile t+2 at step t targets buf[(t+2)%3] = buffer last read at step t-1;
// the top-of-step barrier proves those reads complete (each wave lgkm-drains before
// its MFMAs). vmcnt(8) after issuing covers tile t (FIFO). 48 KB LDS -> 3 blocks/CU.
__global__ __launch_bounds__(256, 3) void egemm_kernel(
    const ushort* __restrict__ Ab, const ushort* __restrict__ Bb,
    const float* __restrict__ bias,
    const int* __restrict__ list, const float* __restrict__ listw,
    const int* __restrict__ counts, ushort* __restrict__ contrib) {
  __shared__ ushort As[3][128 * 32];
  __shared__ ushort Bs[3][128 * 32];
  const int tid = threadIdx.x, lane = tid & 63, wave = tid >> 6;
  const int p = blockIdx.x;
  const int cx = p & 7, q = p >> 3, ct = q & 7, g = ((q >> 3) << 3) | cx;
  const int e = g >> 6, rt = g & 63;
  int count = counts[e]; if (count > CAP) count = CAP;
  if (rt * 128 >= count) return;

  const int cc0 = wave * 2;
  const int rl0 = cc0 * 16 + (lane >> 2);
  const int rl1 = rl0 + 16;
  const int swz8 = (((lane & 3) ^ ((lane >> 3) & 3))) * 8;

  int r0 = rt * 128 + rl0, r1 = rt * 128 + rl1;
  int t0 = (r0 < count) ? (list[e * CAP + r0] & 0xFFFF) : 0;
  int t1 = (r1 < count) ? (list[e * CAP + r1] & 0xFFFF) : 0;
  const ushort* srcA0 = Ab + (size_t)t0 * HID + swz8;
  const ushort* srcA1 = Ab + (size_t)t1 * HID + swz8;
  const ushort* Bbase = Bb + (size_t)e * HID * HID;
  const ushort* srcB0 = Bbase + (size_t)(ct * 128 + rl0) * HID + swz8;
  const ushort* srcB1 = Bbase + (size_t)(ct * 128 + rl1) * HID + swz8;

  f32x4 acc[4][4];
#pragma unroll
  for (int m = 0; m < 4; m++)
#pragma unroll
    for (int n = 0; n < 4; n++) acc[m][n] = (f32x4){0.f, 0.f, 0.f, 0.f};

  const int wm = wave >> 1, wn = wave & 1;
  const int fr = lane & 15, fq = lane >> 4;
  const int sa = (fq ^ ((fr >> 1) & 3)) * 8;

  ushort* dA0 = &As[0][cc0 * 512];
  ushort* dA1 = &As[1][cc0 * 512];
  ushort* dA2 = &As[2][cc0 * 512];
  ushort* dB0 = &Bs[0][cc0 * 512];
  ushort* dB1 = &Bs[1][cc0 * 512];
  ushort* dB2 = &Bs[2][cc0 * 512];
  const ushort* aR0 = &As[0][(wm * 64 + fr) * 32 + sa];
  const ushort* aR1 = &As[1][(wm * 64 + fr) * 32 + sa];
  const ushort* aR2 = &As[2][(wm * 64 + fr) * 32 + sa];
  const ushort* bR0 = &Bs[0][(wn * 64 + fr) * 32 + sa];
  const ushort* bR1 = &Bs[1][(wn * 64 + fr) * 32 + sa];
  const ushort* bR2 = &Bs[2][(wn * 64 + fr) * 32 + sa];

#define EDA(J) ((J) == 0 ? dA0 : (J) == 1 ? dA1 : dA2)
#define EDB(J) ((J) == 0 ? dB0 : (J) == 1 ? dB1 : dB2)
#define ERA(J) ((J) == 0 ? aR0 : (J) == 1 ? aR1 : aR2)
#define ERB(J) ((J) == 0 ? bR0 : (J) == 1 ? bR1 : bR2)
#define ESTG(K0, J) do { \
    gl16(srcA0 + (K0), EDA(J)); gl16(srcA1 + (K0), EDA(J) + 512); \
    gl16(srcB0 + (K0), EDB(J)); gl16(srcB1 + (K0), EDB(J) + 512); } while (0)
#define EKS(T) do { \
    __builtin_amdgcn_s_barrier(); \
    asm volatile("" ::: "memory"); \
    if ((T) + 2 < 32) ESTG(((T) + 2) * 32, ((T) + 2) % 3); \
    if ((T) < 30)      asm volatile("s_waitcnt vmcnt(8)" ::: "memory"); \
    else if ((T) == 30) asm volatile("s_waitcnt vmcnt(4)" ::: "memory"); \
    else                asm volatile("s_waitcnt vmcnt(0)" ::: "memory"); \
    LDFRAGS(ERA((T) % 3), ERB((T) % 3)); \
    MF16; } while (0)

  ESTG(0, 0); ESTG(32, 1);
  EKS(0);  EKS(1);  EKS(2);  EKS(3);  EKS(4);  EKS(5);  EKS(6);  EKS(7);
  EKS(8);  EKS(9);  EKS(10); EKS(11); EKS(12); EKS(13); EKS(14); EKS(15);
  EKS(16); EKS(17); EKS(18); EKS(19); EKS(20); EKS(21); EKS(22); EKS(23);
  EKS(24); EKS(25); EKS(26); EKS(27); EKS(28); EKS(29); EKS(30); EKS(31);
#undef ESTG
#undef EKS
#undef EDA
#undef EDB
#undef ERA
#undef ERB

  // epilogue: batched meta loads + rcp-based sigmoid
  const int colb = ct * 128 + wn * 64 + fr;
  float bc[4];
#pragma unroll
  for (int n = 0; n < 4; n++) bc[n] = bias[e * HID + colb + n * 16];
  const int rb = rt * 128 + wm * 64 + fq * 4;
  int ents[16]; float ws[16];
#pragma unroll
  for (int m = 0; m < 4; m++)
#pragma unroll
    for (int rr = 0; rr < 4; rr++) {
      int r = rb + m * 16 + rr;
      bool v = (r < count);
      ents[m * 4 + rr] = v ? list[e * CAP + r] : -1;
      ws[m * 4 + rr]   = v ? listw[e * CAP + r] : 0.f;
    }
#pragma unroll
  for (int m = 0; m < 4; m++) {
#pragma unroll
    for (int rr = 0; rr < 4; rr++) {
      int ent = ents[m * 4 + rr];
      if (ent >= 0) {
        int tok = ent & 0xFFFF;
        int slot = (ent >> 16) & 1;
        float wgt = ws[m * 4 + rr];
        ushort* dst = contrib + ((size_t)slot * NTOK + tok) * HID;
#pragma unroll
        for (int n = 0; n < 4; n++) {
          float v = acc[m][n][rr] + bc[n];
          float sv = v * __builtin_amdgcn_rcpf(1.0f + __expf(-v));
          dst[colb + n * 16] = f2bf(sv * wgt);
        }
      }
    }
  }
}

// ---------------- combine GEMM with fused mix, fully unrolled K ----------------
__global__ __launch_bounds__(256) void cgemm_kernel(
    const ushort* __restrict__ Cb, const ushort* __restrict__ Bb,
    float* __restrict__ outp) {
  __shared__ ushort As[2][128 * 32];
  __shared__ ushort Bs[2][128 * 32];
  const int tid = threadIdx.x, lane = tid & 63, wave = tid >> 6;
  const int p = blockIdx.x;
  const int cx = p & 7, q = p >> 3, ct = q & 7, rt = ((q >> 3) << 3) | cx;  // rt < 128

  const int cc0 = wave * 2;
  const int rl0 = cc0 * 16 + (lane >> 2);
  const int rl1 = rl0 + 16;
  const int nat8 = (lane & 3) * 8;
  const int swz8 = (((lane & 3) ^ ((lane >> 3) & 3))) * 8;

  const ushort* srcB0 = Bb + (size_t)(ct * 128 + rl0) * HID + swz8;
  const ushort* srcB1 = Bb + (size_t)(ct * 128 + rl1) * HID + swz8;
  const ushort* sA0c0 = Cb + (size_t)(rt * 128 + rl0) * HID + nat8;
  const ushort* sA0c1 = sA0c0 + (size_t)NTOK * HID;
  const ushort* sA1c0 = Cb + (size_t)(rt * 128 + rl1) * HID + nat8;
  const ushort* sA1c1 = sA1c0 + (size_t)NTOK * HID;

  f32x4 acc[4][4];
#pragma unroll
  for (int m = 0; m < 4; m++)
#pragma unroll
    for (int n = 0; n < 4; n++) acc[m][n] = (f32x4){0.f, 0.f, 0.f, 0.f};

  const int wm = wave >> 1, wn = wave & 1;
  const int fr = lane & 15, fq = lane >> 4;
  const int sa = (fq ^ ((fr >> 1) & 3)) * 8;

  ushort* dB0 = &Bs[0][cc0 * 512];
  ushort* dB1 = &Bs[1][cc0 * 512];
  const int wA0 = rl0 * 32 + swz8;
  const int wA1 = rl1 * 32 + swz8;
  ushort* wAd0a = &As[0][wA0]; ushort* wAd0b = &As[0][wA1];
  ushort* wAd1a = &As[1][wA0]; ushort* wAd1b = &As[1][wA1];
  const ushort* aR0 = &As[0][(wm * 64 + fr) * 32 + sa];
  const ushort* aR1 = &As[1][(wm * 64 + fr) * 32 + sa];
  const ushort* bR0 = &Bs[0][(wn * 64 + fr) * 32 + sa];
  const ushort* bR1 = &Bs[1][(wn * 64 + fr) * 32 + sa];

  auto bfadd8 = [](short8 a, short8 b) {
    union { short8 s; uint32_t u[4]; } o;
#pragma unroll
    for (int j = 0; j < 4; j++) {
      float x0 = bf2f((ushort)a[2 * j])     + bf2f((ushort)b[2 * j]);
      float x1 = bf2f((ushort)a[2 * j + 1]) + bf2f((ushort)b[2 * j + 1]);
      uint32_t pk;
      asm("v_cvt_pk_bf16_f32 %0, %1, %2" : "=v"(pk) : "v"(x0), "v"(x1));
      o.u[j] = pk;
    }
    return o.s;
  };

  short8 na0, nb0, na1, nb1;
  gl16(srcB0, dB0); gl16(srcB1, dB0 + 512);
  na0 = *(const short8*)(sA0c0); nb0 = *(const short8*)(sA0c1);
  na1 = *(const short8*)(sA1c0); nb1 = *(const short8*)(sA1c1);
  gl16(srcB0 + 32, dB1); gl16(srcB1 + 32, dB1 + 512);
  *(short8*)wAd0a = bfadd8(na0, nb0);
  *(short8*)wAd0b = bfadd8(na1, nb1);
  na0 = *(const short8*)(sA0c0 + 32); nb0 = *(const short8*)(sA0c1 + 32);
  na1 = *(const short8*)(sA1c0 + 32); nb1 = *(const short8*)(sA1c1 + 32);
  asm volatile("s_waitcnt lgkmcnt(0)" ::: "memory");
  __builtin_amdgcn_s_barrier();

#define CKS(T) do { \
    LDFRAGS(((T) & 1) ? aR1 : aR0, ((T) & 1) ? bR1 : bR0); \
    MF16; \
    if ((T) + 1 < 32) { \
      short8 w0 = bfadd8(na0, nb0); \
      short8 w1 = bfadd8(na1, nb1); \
      *(short8*)((((T) + 1) & 1) ? wAd1a : wAd0a) = w0; \
      *(short8*)((((T) + 1) & 1) ? wAd1b : wAd0b) = w1; \
    } \
    asm volatile("s_waitcnt lgkmcnt(0)" ::: "memory"); \
    __builtin_amdgcn_s_barrier(); \
    if ((T) + 2 < 32) { \
      gl16(srcB0 + ((T) + 2) * 32, ((T) & 1) ? dB1 : dB0); \
      gl16(srcB1 + ((T) + 2) * 32, (((T) & 1) ? dB1 : dB0) + 512); \
      na0 = *(const short8*)(sA0c0 + ((T) + 2) * 32); \
      nb0 = *(const short8*)(sA0c1 + ((T) + 2) * 32); \
      na1 = *(const short8*)(sA1c0 + ((T) + 2) * 32); \
      nb1 = *(const short8*)(sA1c1 + ((T) + 2) * 32); \
    } } while (0)

  CKS(0);  CKS(1);  CKS(2);  CKS(3);  CKS(4);  CKS(5);  CKS(6);  CKS(7);
  CKS(8);  CKS(9);  CKS(10); CKS(11); CKS(12); CKS(13); CKS(14); CKS(15);
  CKS(16); CKS(17); CKS(18); CKS(19); CKS(20); CKS(21); CKS(22); CKS(23);
  CKS(24); CKS(25); CKS(26); CKS(27); CKS(28); CKS(29); CKS(30); CKS(31);
#undef CKS

  const int colb = ct * 128 + wn * 64 + fr;
#pragma unroll
  for (int m = 0; m < 4; m++)
#pragma unroll
    for (int rr = 0; rr < 4; rr++) {
      int r = rt * 128 + wm * 64 + m * 16 + fq * 4 + rr;
      float* dst = outp + (size_t)r * HID;
#pragma unroll
      for (int n = 0; n < 4; n++) dst[colb + n * 16] = acc[m][n][rr];
    }
}

extern "C" void kernel_launch(void* const* d_in, const int* in_sizes, int n_in,
                              void* d_out, int out_size, void* d_ws, size_t ws_size,
                              hipStream_t stream) {
  const float* tokens    = (const float*)d_in[0];
  const float* gate_w    = (const float*)d_in[1];
  const float* expert_w  = (const float*)d_in[2];
  const float* expert_b  = (const float*)d_in[3];
  const float* combine_w = (const float*)d_in[4];
  float* outp = (float*)d_out;

  char* p = (char*)d_ws;
  ushort* Xb  = (ushort*)p; p += (size_t)NTOK * HID * 2;        // 33.5 MB
  ushort* Wxb = (ushort*)p; p += (size_t)NEXP * HID * HID * 2;  // 16.8 MB
  ushort* Wcb = (ushort*)p; p += (size_t)HID * HID * 2;         //  2.1 MB
  ushort* ctb = (ushort*)p; p += (size_t)2 * NTOK * HID * 2;    // 67.1 MB
  int*   list = (int*)p;    p += (size_t)NEXP * CAP * 4;
  float* lsw  = (float*)p;  p += (size_t)NEXP * CAP * 4;
  int*   cnts = (int*)p;    p += 256;
  uint32_t* tinfo = (uint32_t*)p; p += (size_t)NTOK * 4;
  float2*   twp   = (float2*)p;   p += (size_t)NTOK * 8;

  zero_kernel<<<1, 64, 0, stream>>>(cnts);
  gate_cvt_kernel<<<3328, 256, 0, stream>>>(tokens, gate_w, expert_w, combine_w,
                                            Xb, Wxb, Wcb, tinfo, twp);
  scatter_kernel<<<64, 256, 0, stream>>>(tinfo, twp, list, lsw, cnts);
  egemm_kernel<<<4096, 256, 0, stream>>>(Xb, Wxb, expert_b, list, lsw, cnts, ctb);
  cgemm_kernel<<<1024, 256, 0, stream>>>(ctb, Wcb, outp);
}

// Round 10
// 204.232 us; speedup vs baseline: 1.2869x; 1.0691x over previous
//
#include <hip/hip_runtime.h>
#include <stdint.h>

#define HID 1024
#define NEXP 8
#define NTOK 16384
#define CAP 8192

typedef __attribute__((ext_vector_type(8))) __bf16 bf16x8;
typedef __attribute__((ext_vector_type(8))) short short8;
typedef __attribute__((ext_vector_type(4))) float f32x4;

__device__ __forceinline__ ushort f2bf(float f) {
  uint32_t u = __builtin_bit_cast(uint32_t, f);
  u += 0x7FFF + ((u >> 16) & 1);          // round-to-nearest-even
  return (ushort)(u >> 16);
}
__device__ __forceinline__ float bf2f(ushort u) {
  return __builtin_bit_cast(float, (uint32_t)u << 16);
}

__device__ __forceinline__ void gl16(const void* g, void* l) {
  __builtin_amdgcn_global_load_lds((__attribute__((address_space(1))) void*)(g),
                                   (__attribute__((address_space(3))) void*)(l),
                                   16, 0, 0);
}

__global__ void zero_kernel(int* counts) {
  if (threadIdx.x < 16) counts[threadIdx.x] = 0;
}

// ---------------- fused gate + weight conversions (concurrent BW streams) ----------------
__global__ __launch_bounds__(256) void gate_cvt_kernel(
    const float* __restrict__ tokens, const float* __restrict__ gate_w,
    const float* __restrict__ expert_w, const float* __restrict__ combine_w,
    ushort* __restrict__ Xb, ushort* __restrict__ Wxb, ushort* __restrict__ Wcb,
    uint32_t* __restrict__ tinfo, float2* __restrict__ tw) {
  const int b = blockIdx.x;
  if (b >= 2048) {
    const float* src; ushort* dst; int n4, i, stride;
    if (b < 3072) { src = expert_w;  dst = Wxb; n4 = NEXP * HID * HID / 4;
                    i = (b - 2048) * 256 + threadIdx.x; stride = 1024 * 256; }
    else          { src = combine_w; dst = Wcb; n4 = HID * HID / 4;
                    i = (b - 3072) * 256 + threadIdx.x; stride = 256 * 256; }
    for (; i < n4; i += stride) {
      float4 v = reinterpret_cast<const float4*>(src)[i];
      reinterpret_cast<ushort4*>(dst)[i] =
          make_ushort4(f2bf(v.x), f2bf(v.y), f2bf(v.z), f2bf(v.w));
    }
    return;
  }
  const int lane = threadIdx.x & 63;
  const int wave = threadIdx.x >> 6;
  float4 rg[NEXP][4];
#pragma unroll
  for (int e = 0; e < NEXP; e++)
#pragma unroll
    for (int j = 0; j < 4; j++)
      rg[e][j] = reinterpret_cast<const float4*>(gate_w)[e * 256 + j * 64 + lane];

  const int gwid = b * 4 + wave;
  const int nw = 2048 * 4;
  for (int t = gwid; t < NTOK; t += nw) {
    const float4* xr = reinterpret_cast<const float4*>(tokens + (size_t)t * HID);
    float acc[NEXP];
#pragma unroll
    for (int e = 0; e < NEXP; e++) acc[e] = 0.f;
    ushort4 xs[4];
#pragma unroll
    for (int j = 0; j < 4; j++) {
      float4 x = xr[j * 64 + lane];
      xs[j] = make_ushort4(f2bf(x.x), f2bf(x.y), f2bf(x.z), f2bf(x.w));
#pragma unroll
      for (int e = 0; e < NEXP; e++) {
        acc[e] = fmaf(x.x, rg[e][j].x,
                 fmaf(x.y, rg[e][j].y,
                 fmaf(x.z, rg[e][j].z,
                 fmaf(x.w, rg[e][j].w, acc[e]))));
      }
    }
    ushort4* xo = reinterpret_cast<ushort4*>(Xb + (size_t)t * HID);
#pragma unroll
    for (int j = 0; j < 4; j++) xo[j * 64 + lane] = xs[j];
#pragma unroll
    for (int e = 0; e < NEXP; e++) {
#pragma unroll
      for (int s = 32; s > 0; s >>= 1) acc[e] += __shfl_xor(acc[e], s);
    }
    int i1 = 0;
#pragma unroll
    for (int e = 1; e < NEXP; e++) if (acc[e] > acc[i1]) i1 = e;
    int i2 = (i1 == 0) ? 1 : 0;
#pragma unroll
    for (int e = 0; e < NEXP; e++) if (e != i1 && acc[e] > acc[i2]) i2 = e;
    float m = acc[i1];
    float s = 0.f;
#pragma unroll
    for (int e = 0; e < NEXP; e++) s += __expf(acc[e] - m);
    float w1 = 1.f / s;
    float w2 = __expf(acc[i2] - m) / s;
    if (lane == 0) {
      tinfo[t] = (uint32_t)i1 | ((uint32_t)i2 << 8);
      tw[t] = make_float2(w1, w2);
    }
  }
}

// ---------------- scatter: block-aggregated list build ----------------
__global__ __launch_bounds__(256) void scatter_kernel(
    const uint32_t* __restrict__ tinfo, const float2* __restrict__ tw,
    int* __restrict__ list, float* __restrict__ listw, int* __restrict__ counts) {
  __shared__ int lhist[NEXP];
  __shared__ int gbase[NEXP];
  const int tid = threadIdx.x;
  if (tid < NEXP) lhist[tid] = 0;
  __syncthreads();
  const int t = blockIdx.x * 256 + tid;
  uint32_t info = tinfo[t];
  int i1 = info & 0xFF, i2 = (info >> 8) & 0xFF;
  float2 w = tw[t];
  int lr1 = atomicAdd(&lhist[i1], 1);
  int lr2 = atomicAdd(&lhist[i2], 1);
  __syncthreads();
  if (tid < NEXP) gbase[tid] = atomicAdd(&counts[tid], lhist[tid]);
  __syncthreads();
  int p1 = gbase[i1] + lr1;
  if (p1 < CAP) { list[i1 * CAP + p1] = t;           listw[i1 * CAP + p1] = w.x; }
  int p2 = gbase[i2] + lr2;
  if (p2 < CAP) { list[i2 * CAP + p2] = t | 0x10000; listw[i2 * CAP + p2] = w.y; }
}

// fragment loads: 4 A rows (64 rows span), 8 B cols (128 cols span); 32 MFMA
#define LDA4(AB) \
    bf16x8 av0 = *(const bf16x8*)(AB);          bf16x8 av1 = *(const bf16x8*)((AB) + 512); \
    bf16x8 av2 = *(const bf16x8*)((AB) + 1024); bf16x8 av3 = *(const bf16x8*)((AB) + 1536);
#define LDB8(BB) \
    bf16x8 bv0 = *(const bf16x8*)(BB);          bf16x8 bv1 = *(const bf16x8*)((BB) + 512); \
    bf16x8 bv2 = *(const bf16x8*)((BB) + 1024); bf16x8 bv3 = *(const bf16x8*)((BB) + 1536); \
    bf16x8 bv4 = *(const bf16x8*)((BB) + 2048); bf16x8 bv5 = *(const bf16x8*)((BB) + 2560); \
    bf16x8 bv6 = *(const bf16x8*)((BB) + 3072); bf16x8 bv7 = *(const bf16x8*)((BB) + 3584);
#define MFROW(M, AV) do { \
    acc[M][0] = __builtin_amdgcn_mfma_f32_16x16x32_bf16(AV, bv0, acc[M][0], 0, 0, 0); \
    acc[M][1] = __builtin_amdgcn_mfma_f32_16x16x32_bf16(AV, bv1, acc[M][1], 0, 0, 0); \
    acc[M][2] = __builtin_amdgcn_mfma_f32_16x16x32_bf16(AV, bv2, acc[M][2], 0, 0, 0); \
    acc[M][3] = __builtin_amdgcn_mfma_f32_16x16x32_bf16(AV, bv3, acc[M][3], 0, 0, 0); \
    acc[M][4] = __builtin_amdgcn_mfma_f32_16x16x32_bf16(AV, bv4, acc[M][4], 0, 0, 0); \
    acc[M][5] = __builtin_amdgcn_mfma_f32_16x16x32_bf16(AV, bv5, acc[M][5], 0, 0, 0); \
    acc[M][6] = __builtin_amdgcn_mfma_f32_16x16x32_bf16(AV, bv6, acc[M][6], 0, 0, 0); \
    acc[M][7] = __builtin_amdgcn_mfma_f32_16x16x32_bf16(AV, bv7, acc[M][7], 0, 0, 0); } while (0)
#define MF32 do { MFROW(0, av0); MFROW(1, av1); MFROW(2, av2); MFROW(3, av3); } while (0)

// ---------------- expert GEMM: 128x256x32, 3-buffer rotation, one barrier/step ----------------
__global__ __launch_bounds__(256, 2) void egemm_kernel(
    const ushort* __restrict__ Ab, const ushort* __restrict__ Bb,
    const float* __restrict__ bias,
    const int* __restrict__ list, const float* __restrict__ listw,
    const int* __restrict__ counts, ushort* __restrict__ contrib) {
  __shared__ ushort As[3][128 * 32];   // 24 KB
  __shared__ ushort Bs[3][256 * 32];   // 48 KB
  const int tid = threadIdx.x, lane = tid & 63, wave = tid >> 6;
  const int p = blockIdx.x;
  const int ct = (p >> 3) & 3;
  const int gg = ((p >> 5) << 3) | (p & 7);   // 4 ct-blocks of (e,rt) share p%8 (XCD)
  const int e = gg >> 6, rt = gg & 63;
  int count = counts[e]; if (count > CAP) count = CAP;
  if (rt * 128 >= count) return;

  const int rl0 = wave * 32 + (lane >> 2);
  const int rl1 = rl0 + 16;
  const int swz8 = (((lane & 3) ^ ((lane >> 3) & 3))) * 8;

  int r0 = rt * 128 + rl0, r1 = rt * 128 + rl1;
  int t0 = (r0 < count) ? (list[e * CAP + r0] & 0xFFFF) : 0;
  int t1 = (r1 < count) ? (list[e * CAP + r1] & 0xFFFF) : 0;
  const ushort* srcA0 = Ab + (size_t)t0 * HID + swz8;
  const ushort* srcA1 = Ab + (size_t)t1 * HID + swz8;
  const ushort* Bbase = Bb + (size_t)e * HID * HID;
  const int brow = ct * 256 + wave * 64 + (lane >> 2);
  const ushort* srcB0 = Bbase + (size_t)brow * HID + swz8;
  const ushort* srcB1 = srcB0 + (size_t)16 * HID;
  const ushort* srcB2 = srcB0 + (size_t)32 * HID;
  const ushort* srcB3 = srcB0 + (size_t)48 * HID;

  f32x4 acc[4][8];
#pragma unroll
  for (int m = 0; m < 4; m++)
#pragma unroll
    for (int n = 0; n < 8; n++) acc[m][n] = (f32x4){0.f, 0.f, 0.f, 0.f};

  const int wm = wave >> 1, wn = wave & 1;
  const int fr = lane & 15, fq = lane >> 4;
  const int sa = (fq ^ ((fr >> 1) & 3)) * 8;

  ushort* dA0 = &As[0][wave * 1024];
  ushort* dA1 = &As[1][wave * 1024];
  ushort* dA2 = &As[2][wave * 1024];
  ushort* dB0 = &Bs[0][wave * 2048];
  ushort* dB1 = &Bs[1][wave * 2048];
  ushort* dB2 = &Bs[2][wave * 2048];
  const ushort* aR0 = &As[0][(wm * 64 + fr) * 32 + sa];
  const ushort* aR1 = &As[1][(wm * 64 + fr) * 32 + sa];
  const ushort* aR2 = &As[2][(wm * 64 + fr) * 32 + sa];
  const ushort* bR0 = &Bs[0][(wn * 128 + fr) * 32 + sa];
  const ushort* bR1 = &Bs[1][(wn * 128 + fr) * 32 + sa];
  const ushort* bR2 = &Bs[2][(wn * 128 + fr) * 32 + sa];

#define EDA(J) ((J) == 0 ? dA0 : (J) == 1 ? dA1 : dA2)
#define EDB(J) ((J) == 0 ? dB0 : (J) == 1 ? dB1 : dB2)
#define ERA(J) ((J) == 0 ? aR0 : (J) == 1 ? aR1 : aR2)
#define ERB(J) ((J) == 0 ? bR0 : (J) == 1 ? bR1 : bR2)
#define ESTG(K0, J) do { \
    gl16(srcA0 + (K0), EDA(J)); gl16(srcA1 + (K0), EDA(J) + 512); \
    gl16(srcB0 + (K0), EDB(J));        gl16(srcB1 + (K0), EDB(J) + 512); \
    gl16(srcB2 + (K0), EDB(J) + 1024); gl16(srcB3 + (K0), EDB(J) + 1536); } while (0)
#define EKS(T) do { \
    __builtin_amdgcn_s_barrier(); \
    asm volatile("" ::: "memory"); \
    if ((T) + 2 < 32) ESTG(((T) + 2) * 32, ((T) + 2) % 3); \
    if ((T) < 30)       asm volatile("s_waitcnt vmcnt(12)" ::: "memory"); \
    else if ((T) == 30) asm volatile("s_waitcnt vmcnt(6)" ::: "memory"); \
    else                asm volatile("s_waitcnt vmcnt(0)" ::: "memory"); \
    LDA4(ERA((T) % 3)); LDB8(ERB((T) % 3)); \
    MF32; } while (0)

  ESTG(0, 0); ESTG(32, 1);
  EKS(0);  EKS(1);  EKS(2);  EKS(3);  EKS(4);  EKS(5);  EKS(6);  EKS(7);
  EKS(8);  EKS(9);  EKS(10); EKS(11); EKS(12); EKS(13); EKS(14); EKS(15);
  EKS(16); EKS(17); EKS(18); EKS(19); EKS(20); EKS(21); EKS(22); EKS(23);
  EKS(24); EKS(25); EKS(26); EKS(27); EKS(28); EKS(29); EKS(30); EKS(31);
#undef ESTG
#undef EKS
#undef EDA
#undef EDB
#undef ERA
#undef ERB

  // epilogue: batched meta loads + rcp-based sigmoid, 8 columns
  const int colb = ct * 256 + wn * 128 + fr;
  float bc[8];
#pragma unroll
  for (int n = 0; n < 8; n++) bc[n] = bias[e * HID + colb + n * 16];
  const int rb = rt * 128 + wm * 64 + fq * 4;
  int ents[16]; float ws[16];
#pragma unroll
  for (int m = 0; m < 4; m++)
#pragma unroll
    for (int rr = 0; rr < 4; rr++) {
      int r = rb + m * 16 + rr;
      bool v = (r < count);
      ents[m * 4 + rr] = v ? list[e * CAP + r] : -1;
      ws[m * 4 + rr]   = v ? listw[e * CAP + r] : 0.f;
    }
#pragma unroll
  for (int m = 0; m < 4; m++) {
#pragma unroll
    for (int rr = 0; rr < 4; rr++) {
      int ent = ents[m * 4 + rr];
      if (ent >= 0) {
        int tok = ent & 0xFFFF;
        int slot = (ent >> 16) & 1;
        float wgt = ws[m * 4 + rr];
        ushort* dst = contrib + ((size_t)slot * NTOK + tok) * HID;
#pragma unroll
        for (int n = 0; n < 8; n++) {
          float v = acc[m][n][rr] + bc[n];
          float sv = v * __builtin_amdgcn_rcpf(1.0f + __expf(-v));
          dst[colb + n * 16] = f2bf(sv * wgt);
        }
      }
    }
  }
}

// ---------------- combine GEMM 128x256x32 with fused mix (A = c0+c1) ----------------
__global__ __launch_bounds__(256, 2) void cgemm_kernel(
    const ushort* __restrict__ Cb, const ushort* __restrict__ Bb,
    float* __restrict__ outp) {
  __shared__ ushort As[2][128 * 32];   // 16 KB
  __shared__ ushort Bs[2][256 * 32];   // 32 KB
  const int tid = threadIdx.x, lane = tid & 63, wave = tid >> 6;
  const int p = blockIdx.x;                 // 512 blocks
  const int ct = (p >> 3) & 3;
  const int rt = ((p >> 5) << 3) | (p & 7); // rt < 128

  const int rl0 = wave * 32 + (lane >> 2);
  const int rl1 = rl0 + 16;
  const int nat8 = (lane & 3) * 8;
  const int swz8 = (((lane & 3) ^ ((lane >> 3) & 3))) * 8;

  const int brow = ct * 256 + wave * 64 + (lane >> 2);
  const ushort* srcB0 = Bb + (size_t)brow * HID + swz8;
  const ushort* srcB1 = srcB0 + (size_t)16 * HID;
  const ushort* srcB2 = srcB0 + (size_t)32 * HID;
  const ushort* srcB3 = srcB0 + (size_t)48 * HID;
  const ushort* sA0c0 = Cb + (size_t)(rt * 128 + rl0) * HID + nat8;
  const ushort* sA0c1 = sA0c0 + (size_t)NTOK * HID;
  const ushort* sA1c0 = Cb + (size_t)(rt * 128 + rl1) * HID + nat8;
  const ushort* sA1c1 = sA1c0 + (size_t)NTOK * HID;

  f32x4 acc[4][8];
#pragma unroll
  for (int m = 0; m < 4; m++)
#pragma unroll
    for (int n = 0; n < 8; n++) acc[m][n] = (f32x4){0.f, 0.f, 0.f, 0.f};

  const int wm = wave >> 1, wn = wave & 1;
  const int fr = lane & 15, fq = lane >> 4;
  const int sa = (fq ^ ((fr >> 1) & 3)) * 8;

  ushort* dB0 = &Bs[0][wave * 2048];
  ushort* dB1 = &Bs[1][wave * 2048];
  const int wA0 = rl0 * 32 + swz8;
  const int wA1 = rl1 * 32 + swz8;
  ushort* wAd0a = &As[0][wA0]; ushort* wAd0b = &As[0][wA1];
  ushort* wAd1a = &As[1][wA0]; ushort* wAd1b = &As[1][wA1];
  const ushort* aR0 = &As[0][(wm * 64 + fr) * 32 + sa];
  const ushort* aR1 = &As[1][(wm * 64 + fr) * 32 + sa];
  const ushort* bR0 = &Bs[0][(wn * 128 + fr) * 32 + sa];
  const ushort* bR1 = &Bs[1][(wn * 128 + fr) * 32 + sa];

  auto bfadd8 = [](short8 a, short8 b) {
    union { short8 s; uint32_t u[4]; } o;
#pragma unroll
    for (int j = 0; j < 4; j++) {
      float x0 = bf2f((ushort)a[2 * j])     + bf2f((ushort)b[2 * j]);
      float x1 = bf2f((ushort)a[2 * j + 1]) + bf2f((ushort)b[2 * j + 1]);
      uint32_t pk;
      asm("v_cvt_pk_bf16_f32 %0, %1, %2" : "=v"(pk) : "v"(x0), "v"(x1));
      o.u[j] = pk;
    }
    return o.s;
  };

#define CSTB(K0, J) do { \
    gl16(srcB0 + (K0), (J) ? dB1 : dB0);        gl16(srcB1 + (K0), ((J) ? dB1 : dB0) + 512); \
    gl16(srcB2 + (K0), ((J) ? dB1 : dB0) + 1024); gl16(srcB3 + (K0), ((J) ? dB1 : dB0) + 1536); } while (0)

  short8 na0, nb0, na1, nb1;
  CSTB(0, 0);
  na0 = *(const short8*)(sA0c0); nb0 = *(const short8*)(sA0c1);
  na1 = *(const short8*)(sA1c0); nb1 = *(const short8*)(sA1c1);
  CSTB(32, 1);
  *(short8*)wAd0a = bfadd8(na0, nb0);
  *(short8*)wAd0b = bfadd8(na1, nb1);
  na0 = *(const short8*)(sA0c0 + 32); nb0 = *(const short8*)(sA0c1 + 32);
  na1 = *(const short8*)(sA1c0 + 32); nb1 = *(const short8*)(sA1c1 + 32);
  asm volatile("s_waitcnt lgkmcnt(0)" ::: "memory");
  __builtin_amdgcn_s_barrier();

#define CKS(T) do { \
    LDA4(((T) & 1) ? aR1 : aR0); LDB8(((T) & 1) ? bR1 : bR0); \
    MF32; \
    if ((T) + 1 < 32) { \
      short8 w0 = bfadd8(na0, nb0); \
      short8 w1 = bfadd8(na1, nb1); \
      *(short8*)((((T) + 1) & 1) ? wAd1a : wAd0a) = w0; \
      *(short8*)((((T) + 1) & 1) ? wAd1b : wAd0b) = w1; \
    } \
    asm volatile("s_waitcnt lgkmcnt(0)" ::: "memory"); \
    __builtin_amdgcn_s_barrier(); \
    if ((T) + 2 < 32) { \
      CSTB(((T) + 2) * 32, (T) & 1); \
      na0 = *(const short8*)(sA0c0 + ((T) + 2) * 32); \
      nb0 = *(const short8*)(sA0c1 + ((T) + 2) * 32); \
      na1 = *(const short8*)(sA1c0 + ((T) + 2) * 32); \
      nb1 = *(const short8*)(sA1c1 + ((T) + 2) * 32); \
    } } while (0)

  CKS(0);  CKS(1);  CKS(2);  CKS(3);  CKS(4);  CKS(5);  CKS(6);  CKS(7);
  CKS(8);  CKS(9);  CKS(10); CKS(11); CKS(12); CKS(13); CKS(14); CKS(15);
  CKS(16); CKS(17); CKS(18); CKS(19); CKS(20); CKS(21); CKS(22); CKS(23);
  CKS(24); CKS(25); CKS(26); CKS(27); CKS(28); CKS(29); CKS(30); CKS(31);
#undef CKS
#undef CSTB

  const int colb = ct * 256 + wn * 128 + fr;
#pragma unroll
  for (int m = 0; m < 4; m++)
#pragma unroll
    for (int rr = 0; rr < 4; rr++) {
      int r = rt * 128 + wm * 64 + m * 16 + fq * 4 + rr;
      float* dst = outp + (size_t)r * HID;
#pragma unroll
      for (int n = 0; n < 8; n++) dst[colb + n * 16] = acc[m][n][rr];
    }
}

extern "C" void kernel_launch(void* const* d_in, const int* in_sizes, int n_in,
                              void* d_out, int out_size, void* d_ws, size_t ws_size,
                              hipStream_t stream) {
  const float* tokens    = (const float*)d_in[0];
  const float* gate_w    = (const float*)d_in[1];
  const float* expert_w  = (const float*)d_in[2];
  const float* expert_b  = (const float*)d_in[3];
  const float* combine_w = (const float*)d_in[4];
  float* outp = (float*)d_out;

  char* p = (char*)d_ws;
  ushort* Xb  = (ushort*)p; p += (size_t)NTOK * HID * 2;        // 33.5 MB
  ushort* Wxb = (ushort*)p; p += (size_t)NEXP * HID * HID * 2;  // 16.8 MB
  ushort* Wcb = (ushort*)p; p += (size_t)HID * HID * 2;         //  2.1 MB
  ushort* ctb = (ushort*)p; p += (size_t)2 * NTOK * HID * 2;    // 67.1 MB
  int*   list = (int*)p;    p += (size_t)NEXP * CAP * 4;
  float* lsw  = (float*)p;  p += (size_t)NEXP * CAP * 4;
  int*   cnts = (int*)p;    p += 256;
  uint32_t* tinfo = (uint32_t*)p; p += (size_t)NTOK * 4;
  float2*   twp   = (float2*)p;   p += (size_t)NTOK * 8;

  zero_kernel<<<1, 64, 0, stream>>>(cnts);
  gate_cvt_kernel<<<3328, 256, 0, stream>>>(tokens, gate_w, expert_w, combine_w,
                                            Xb, Wxb, Wcb, tinfo, twp);
  scatter_kernel<<<64, 256, 0, stream>>>(tinfo, twp, list, lsw, cnts);
  egemm_kernel<<<2048, 256, 0, stream>>>(Xb, Wxb, expert_b, list, lsw, cnts, ctb);
  cgemm_kernel<<<512, 256, 0, stream>>>(ctb, Wcb, outp);
}